// Round 13
// baseline (268.370 us; speedup 1.0000x reference)
//
#include <hip/hip_runtime.h>
#include <hip/hip_cooperative_groups.h>

namespace cg = cooperative_groups;

typedef __attribute__((ext_vector_type(8))) short short8;
typedef __attribute__((ext_vector_type(8))) __bf16 bf16x8;
typedef __attribute__((ext_vector_type(4))) float f32x4;

#define S_LEN 4096
#define EMB   1024
#define NHEAD 16
#define GCHUNK 256
#define NCHUNK (S_LEN / GCHUNK)   // 16

__constant__ int GPOS[8] = {0, 585, 1170, 1755, 2340, 2925, 3510, 4095};

__device__ __forceinline__ unsigned short f2bf(float f) {
    unsigned int u = __float_as_uint(f);
    u += 0x7fffu + ((u >> 16) & 1u);
    return (unsigned short)(u >> 16);
}
__device__ __forceinline__ float bf2f(unsigned short s) {
    return __uint_as_float(((unsigned int)s) << 16);
}
#define GLOAD16(src, dst) __builtin_amdgcn_global_load_lds( \
    (const __attribute__((address_space(1))) void*)(src),    \
    (__attribute__((address_space(3))) void*)(dst), 16, 0, 0)

// ================================================================ mega (cooperative)
__global__ __launch_bounds__(256, 2) void mega(
    const float* __restrict__ x,
    const float* __restrict__ Wq, const float* __restrict__ bq,
    const float* __restrict__ Wk, const float* __restrict__ bk,
    const float* __restrict__ Wv, const float* __restrict__ bv,
    const float* __restrict__ Wo, const float* __restrict__ bo,
    unsigned short* __restrict__ xb, unsigned short* __restrict__ wt,
    unsigned short* __restrict__ qb, unsigned short* __restrict__ kb,
    unsigned short* __restrict__ vb, unsigned short* __restrict__ vtg,
    float* __restrict__ o_part, float* __restrict__ m_l,
    float* __restrict__ Cout, unsigned int* ctrs)
{
    __shared__ __align__(16) char smem[65536];
    const int t = threadIdx.x;
    const int bid = blockIdx.x;
    const int GN = gridDim.x;
    const int lane = t & 63, wave = t >> 6;
    const int wm = wave >> 1, wn = wave & 1;
    const int col16 = lane & 15, grp = lane >> 4;
    cg::grid_group grid = cg::this_grid();
    unsigned short* ab = xb;
    volatile unsigned int* mail = ctrs + 16;

    // ---- phase 0: converts + counter init
    if (bid == 0 && t == 0) { ctrs[0] = 0u; ctrs[1] = 0u; }
    {
        float (*tile)[65] = (float(*)[65])smem;
        for (int wj = bid; wj < 1024; wj += GN) {
            __syncthreads();
            const int w = wj >> 8, rem = wj & 255;
            const int k0 = (rem >> 4) * 64, n0 = (rem & 15) * 64;
            const float* W = (w == 0) ? Wq : (w == 1) ? Wk : (w == 2) ? Wv : Wo;
            unsigned short* dst = wt + (size_t)w * (1u << 20);
            for (int i = t; i < 4096; i += 256) {
                int r = i >> 6, c = i & 63;
                tile[r][c] = W[(size_t)(k0 + r) * EMB + n0 + c];
            }
            __syncthreads();
            for (int i = t; i < 4096; i += 256) {
                int r = i >> 6, c = i & 63;
                dst[(size_t)(n0 + r) * EMB + k0 + c] = f2bf(tile[c][r]);
            }
        }
        const int n4 = S_LEN * EMB / 4;
        const float4* in = (const float4*)x;
        ushort4* out4 = (ushort4*)xb;
        for (int i = bid * 256 + t; i < n4; i += GN * 256) {
            float4 v = in[i];
            ushort4 o;
            o.x = f2bf(v.x); o.y = f2bf(v.y); o.z = f2bf(v.z); o.w = f2bf(v.w);
            out4[i] = o;
        }
    }
    grid.sync();

    // ---- phase 1: QKV GEMM, 768 ticketed jobs
    {
        unsigned short* As0 = (unsigned short*)smem;
        unsigned short* Bs0 = (unsigned short*)(smem + 32768);
        while (true) {
            __syncthreads();
            if (t == 0) mail[bid] = atomicAdd(&ctrs[0], 1u);
            __syncthreads();
            const unsigned int j = mail[bid];
            if (j >= 768u) break;
            const int xcd = j & 7;
            const int li  = j >> 3;
            const int bn  = li >> 2;
            const int bm  = xcd * 4 + (li & 3);
            const int sel = bn >> 3, bn_l = bn & 7;
            const float* bias = (sel == 0) ? bq : (sel == 1) ? bk : bv;
            unsigned short* outp = (sel == 0) ? qb : (sel == 1) ? kb : vb;

            f32x4 acc[4][4] = {};

            auto stage = [&](int buf, int tstep) {
                const int k0 = tstep * 64;
#pragma unroll
                for (int c = 0; c < 4; ++c) {
                    int p = t + 256 * c;
                    int row = p >> 3, s = p & 7, kc = s ^ (row & 7);
                    GLOAD16(xb + (size_t)(bm * 128 + row) * EMB + k0 + kc * 8, As0 + buf * 8192 + p * 8);
                }
#pragma unroll
                for (int c = 0; c < 4; ++c) {
                    int p = t + 256 * c;
                    int row = p >> 3, s = p & 7, kc = s ^ (row & 7);
                    GLOAD16(wt + (size_t)(bn * 128 + row) * EMB + k0 + kc * 8, Bs0 + buf * 8192 + p * 8);
                }
            };
            auto compute = [&](int cur) {
                const unsigned short* Ab = As0 + cur * 8192;
                const unsigned short* Bb = Bs0 + cur * 8192;
#pragma unroll
                for (int kk = 0; kk < 2; ++kk) {
                    const int kc = kk * 4 + grp;
                    bf16x8 af[4], bfr[4];
#pragma unroll
                    for (int f = 0; f < 4; ++f) {
                        int mrow = wm * 64 + f * 16 + col16;
                        short8 ra = *(const short8*)(Ab + (mrow * 8 + (kc ^ (mrow & 7))) * 8);
                        af[f] = __builtin_bit_cast(bf16x8, ra);
                        int nrow = wn * 64 + f * 16 + col16;
                        short8 rb = *(const short8*)(Bb + (nrow * 8 + (kc ^ (nrow & 7))) * 8);
                        bfr[f] = __builtin_bit_cast(bf16x8, rb);
                    }
#pragma unroll
                    for (int fi = 0; fi < 4; ++fi)
#pragma unroll
                        for (int fj = 0; fj < 4; ++fj)
                            acc[fi][fj] = __builtin_amdgcn_mfma_f32_16x16x32_bf16(af[fi], bfr[fj], acc[fi][fj], 0, 0, 0);
                }
            };

            stage(0, 0);
            stage(1, 1);
#pragma unroll 2
            for (int ts = 0; ts < 14; ++ts) {
                const int cur = ts & 1;
                asm volatile("s_waitcnt vmcnt(8)" ::: "memory");
                __builtin_amdgcn_s_barrier();
                compute(cur);
                __builtin_amdgcn_s_barrier();
                stage(cur, ts + 2);
            }
            asm volatile("s_waitcnt vmcnt(8)" ::: "memory");
            __builtin_amdgcn_s_barrier();
            compute(0);
            asm volatile("s_waitcnt vmcnt(0)" ::: "memory");
            __builtin_amdgcn_s_barrier();
            compute(1);

#pragma unroll
            for (int fi = 0; fi < 4; ++fi) {
                const int row0 = bm * 128 + wm * 64 + fi * 16 + grp * 4;
#pragma unroll
                for (int fj = 0; fj < 4; ++fj) {
                    const int col = bn_l * 128 + wn * 64 + fj * 16 + col16;
                    const float bvv = bias[col];
#pragma unroll
                    for (int r = 0; r < 4; ++r)
                        outp[(size_t)(row0 + r) * EMB + col] = f2bf(acc[fi][fj][r] + bvv);
                }
            }

            if (sel == 2) {
                __syncthreads();
                unsigned short* T = As0;
#pragma unroll
                for (int fi = 0; fi < 4; ++fi) {
                    const int row_l = wm * 64 + fi * 16 + grp * 4;
#pragma unroll
                    for (int fj = 0; fj < 4; ++fj) {
                        const int col_l = wn * 64 + fj * 16 + col16;
                        const float bvv = bias[bn_l * 128 + col_l];
#pragma unroll
                        for (int r = 0; r < 4; ++r)
                            T[col_l * 128 + ((row_l + r) ^ ((col_l & 15) << 3))] = f2bf(acc[fi][fj][r] + bvv);
                    }
                }
                __syncthreads();
#pragma unroll
                for (int c = 0; c < 8; ++c) {
                    int q = t + 256 * c;
                    int col = q >> 4, sc = q & 15, s0 = sc * 8;
                    short8 v = *(const short8*)(T + col * 128 + (s0 ^ ((col & 15) << 3)));
                    *(short8*)(vtg + (size_t)(bn_l * 128 + col) * S_LEN + bm * 128 + s0) = v;
                }
            }
        }
    }
    grid.sync();

    // ---- phase 2: attention, 1280 ticketed jobs
    {
        while (true) {
            __syncthreads();
            if (t == 0) mail[bid] = atomicAdd(&ctrs[1], 1u);
            __syncthreads();
            const unsigned int j = mail[bid];
            if (j >= 1280u) break;

            if (j < 1024u) {
                unsigned short* Qs  = (unsigned short*)smem;
                unsigned short* Ks  = Qs + 64 * 64;
                unsigned short* Vts = Ks + 80 * 64;
                unsigned short* Ps  = Vts + 64 * 64;
                float* Pg = (float*)(Ps + 64 * 64);
                float* Vg = Pg + 64 * 9;
                const int h = j >> 6, b = j & 63;
                const int bc = h * 64;

#pragma unroll
                for (int c = 0; c < 2; ++c) {
                    int p = t + 256 * c, row = p >> 3, s = p & 7, kc = s ^ (row & 7);
                    GLOAD16(qb + (size_t)(b * 64 + row) * EMB + bc + kc * 8, Qs + p * 8);
                }
#pragma unroll
                for (int c = 0; c < 3; ++c) {
                    int p = t + 256 * c;
                    if (p < 576) {
                        int row = p >> 3, s = p & 7, kc = s ^ (row & 7);
                        int srow = (row < 64) ? (b * 64 + row) : GPOS[row - 64];
                        GLOAD16(kb + (size_t)srow * EMB + bc + kc * 8, Ks + p * 8);
                    }
                }
                if (t < 64) {
                    short8 z = {};
                    *(short8*)(Ks + (576 + t) * 8) = z;
                }
#pragma unroll
                for (int c = 0; c < 2; ++c) {
                    int p = t + 256 * c, row = p >> 3, s = p & 7, kc = s ^ (row & 7);
                    GLOAD16(vtg + (size_t)(bc + row) * S_LEN + b * 64 + kc * 8, Vts + p * 8);
                }
                for (int i = t; i < 512; i += 256) {
                    int g = i >> 6, d = i & 63;
                    Vg[g * 64 + d] = bf2f(vb[(size_t)GPOS[g] * EMB + bc + d]);
                }
                asm volatile("s_waitcnt vmcnt(0)" ::: "memory");
                __syncthreads();

                f32x4 sc5[5] = {};
                const int arow = wave * 16 + col16;
#pragma unroll
                for (int kk = 0; kk < 2; ++kk) {
                    const int kc = kk * 4 + grp;
                    short8 ra = *(const short8*)(Qs + (arow * 8 + (kc ^ (arow & 7))) * 8);
                    bf16x8 af = __builtin_bit_cast(bf16x8, ra);
#pragma unroll
                    for (int n = 0; n < 5; ++n) {
                        const int brow = n * 16 + col16;
                        short8 rb = *(const short8*)(Ks + (brow * 8 + (kc ^ (brow & 7))) * 8);
                        sc5[n] = __builtin_amdgcn_mfma_f32_16x16x32_bf16(af, __builtin_bit_cast(bf16x8, rb), sc5[n], 0, 0, 0);
                    }
                }

                const bool valid4 = (col16 < 8) && ((GPOS[col16] >> 6) != b);
#pragma unroll
                for (int r = 0; r < 4; ++r) {
                    const int row = wave * 16 + grp * 4 + r;
                    float s[5];
#pragma unroll
                    for (int n = 0; n < 4; ++n) s[n] = sc5[n][r] * 0.125f;
                    s[4] = valid4 ? sc5[4][r] * 0.125f : -1e30f;
                    float m = fmaxf(fmaxf(fmaxf(s[0], s[1]), fmaxf(s[2], s[3])), s[4]);
#pragma unroll
                    for (int off = 1; off < 16; off <<= 1) m = fmaxf(m, __shfl_xor(m, off));
                    float e[5], l = 0.f;
#pragma unroll
                    for (int n = 0; n < 5; ++n) { e[n] = __expf(s[n] - m); l += e[n]; }
#pragma unroll
                    for (int off = 1; off < 16; off <<= 1) l += __shfl_xor(l, off);
                    const float inv = 1.f / l;
#pragma unroll
                    for (int n = 0; n < 4; ++n) {
                        const int col = n * 16 + col16;
                        const int kc = col >> 3;
                        Ps[(row * 8 + (kc ^ (row & 7))) * 8 + (col & 7)] = f2bf(e[n] * inv);
                    }
                    if (col16 < 8) Pg[row * 9 + col16] = e[4] * inv;
                }
                __syncthreads();

                f32x4 oa[4] = {};
#pragma unroll
                for (int kk = 0; kk < 2; ++kk) {
                    const int kc = kk * 4 + grp;
                    short8 ra = *(const short8*)(Ps + (arow * 8 + (kc ^ (arow & 7))) * 8);
                    bf16x8 af = __builtin_bit_cast(bf16x8, ra);
#pragma unroll
                    for (int n = 0; n < 4; ++n) {
                        const int drow = n * 16 + col16;
                        short8 rb = *(const short8*)(Vts + (drow * 8 + (kc ^ (drow & 7))) * 8);
                        oa[n] = __builtin_amdgcn_mfma_f32_16x16x32_bf16(af, __builtin_bit_cast(bf16x8, rb), oa[n], 0, 0, 0);
                    }
                }

                float pgr[4][8];
#pragma unroll
                for (int r = 0; r < 4; ++r) {
                    const int row = wave * 16 + grp * 4 + r;
#pragma unroll
                    for (int g = 0; g < 8; ++g) pgr[r][g] = Pg[row * 9 + g];
                }
#pragma unroll
                for (int n = 0; n < 4; ++n) {
                    const int d = n * 16 + col16;
#pragma unroll
                    for (int g = 0; g < 8; ++g) {
                        const float vg = Vg[g * 64 + d];
#pragma unroll
                        for (int r = 0; r < 4; ++r) oa[n][r] += pgr[r][g] * vg;
                    }
                }

#pragma unroll
                for (int n = 0; n < 4; ++n) {
                    const int d = n * 16 + col16;
#pragma unroll
                    for (int r = 0; r < 4; ++r) {
                        const int row = wave * 16 + grp * 4 + r;
                        ab[(size_t)(b * 64 + row) * EMB + bc + d] = f2bf(oa[n][r]);
                    }
                }
            } else {
                float* Qsf = (float*)smem;
                unsigned short* Vs = (unsigned short*)(smem + 2048);
                float* Ps = (float*)(smem + 2048 + 32768);
                float* mfin = Ps + 8 * 256;
                float* lfin = mfin + 8;

                const int bx = (int)j - 1024;
                const int h = bx >> 4;
                const int ch = bx & (NCHUNK - 1);
                const int bc = h * 64;
                const int k0 = ch * GCHUNK;

                for (int i = t; i < 512; i += 256) {
                    int r = i >> 6, d = i & 63;
                    Qsf[r * 64 + d] = bf2f(qb[(size_t)GPOS[r] * EMB + bc + d]);
                }
                {
                    const unsigned short* vrow = vb + (size_t)(k0 + t) * EMB + bc;
#pragma unroll
                    for (int c = 0; c < 8; ++c) {
                        short8 vv = *(const short8*)(vrow + c * 8);
                        *(short8*)(&Vs[t * 64 + (c ^ (t & 7)) * 8]) = vv;
                    }
                }
                float kf[64];
                {
                    const unsigned short* krow = kb + (size_t)(k0 + t) * EMB + bc;
#pragma unroll
                    for (int c = 0; c < 8; ++c) {
                        short8 kv = *(const short8*)(krow + c * 8);
#pragma unroll
                        for (int jj = 0; jj < 8; ++jj) kf[c * 8 + jj] = bf2f((unsigned short)kv[jj]);
                    }
                }
                __syncthreads();

#pragma unroll
                for (int r = 0; r < 8; ++r) {
                    float a0 = 0.f, a1 = 0.f, a2 = 0.f, a3 = 0.f;
#pragma unroll
                    for (int c4 = 0; c4 < 16; ++c4) {
                        f32x4 q = *(const f32x4*)&Qsf[r * 64 + c4 * 4];
                        a0 += q.x * kf[c4 * 4 + 0];
                        a1 += q.y * kf[c4 * 4 + 1];
                        a2 += q.z * kf[c4 * 4 + 2];
                        a3 += q.w * kf[c4 * 4 + 3];
                    }
                    Ps[r * 256 + t] = (a0 + a1 + a2 + a3) * 0.125f;
                }
                __syncthreads();

#pragma unroll
                for (int rr = 0; rr < 2; ++rr) {
                    const int r = wave * 2 + rr;
                    float v0 = Ps[r * 256 + lane], v1 = Ps[r * 256 + lane + 64],
                          v2 = Ps[r * 256 + lane + 128], v3 = Ps[r * 256 + lane + 192];
                    float m = fmaxf(fmaxf(v0, v1), fmaxf(v2, v3));
#pragma unroll
                    for (int off = 1; off < 64; off <<= 1) m = fmaxf(m, __shfl_xor(m, off));
                    float e0 = __expf(v0 - m), e1 = __expf(v1 - m), e2 = __expf(v2 - m), e3 = __expf(v3 - m);
                    float l = e0 + e1 + e2 + e3;
#pragma unroll
                    for (int off = 1; off < 64; off <<= 1) l += __shfl_xor(l, off);
                    Ps[r * 256 + lane] = e0; Ps[r * 256 + lane + 64] = e1;
                    Ps[r * 256 + lane + 128] = e2; Ps[r * 256 + lane + 192] = e3;
                    if (lane == 0) { mfin[r] = m; lfin[r] = l; }
                }
                __syncthreads();

                const int r = t >> 5;
                const int d0 = (t & 31) * 2;
                const int cc = d0 >> 3, ee = d0 & 7;
                float acc0 = 0.f, acc1 = 0.f;
                for (int k = 0; k < GCHUNK; k += 4) {
                    f32x4 p = *(const f32x4*)&Ps[r * 256 + k];
#pragma unroll
                    for (int jj = 0; jj < 4; ++jj) {
                        unsigned int vv = *(const unsigned int*)&Vs[(k + jj) * 64 + ((cc ^ ((k + jj) & 7)) << 3) + ee];
                        acc0 += p[jj] * bf2f((unsigned short)(vv & 0xffff));
                        acc1 += p[jj] * bf2f((unsigned short)(vv >> 16));
                    }
                }
                const int rowg = h * 8 + r;
                float* od = o_part + ((size_t)rowg * NCHUNK + ch) * 64 + d0;
                od[0] = acc0; od[1] = acc1;
                if ((t & 31) == 0) {
                    m_l[((size_t)rowg * NCHUNK + ch) * 2 + 0] = mfin[r];
                    m_l[((size_t)rowg * NCHUNK + ch) * 2 + 1] = lfin[r];
                }
            }
        }
    }
    grid.sync();

    // ---- phase 3: gcomb
    for (int j = bid; j < 32; j += GN) {
        const int gid = j * 256 + t;
        const int row = gid >> 6, d = gid & 63;
        float M = -1e30f;
#pragma unroll
        for (int c = 0; c < NCHUNK; ++c) M = fmaxf(M, m_l[((size_t)row * NCHUNK + c) * 2]);
        float L = 0.f, o = 0.f;
#pragma unroll
        for (int c = 0; c < NCHUNK; ++c) {
            float w = __expf(m_l[((size_t)row * NCHUNK + c) * 2] - M);
            L += m_l[((size_t)row * NCHUNK + c) * 2 + 1] * w;
            o += o_part[((size_t)row * NCHUNK + c) * 64 + d] * w;
        }
        const int h = row >> 3, gi = row & 7;
        ab[(size_t)GPOS[gi] * EMB + h * 64 + d] = f2bf(o / L);
    }
    grid.sync();

    // ---- phase 4: output GEMM, 512 strided jobs
    for (int j = bid; j < 512; j += GN) {
        __syncthreads();
        unsigned short* As0 = (unsigned short*)smem;
        unsigned short* Bs0 = (unsigned short*)(smem + 32768);
        const int xcd = j & 7;
        const int li  = j >> 3;
        const int bn  = li >> 2;
        const int bm  = xcd * 4 + (li & 3);
        const unsigned short* Bt = wt + (3u << 20);

        f32x4 acc[4][2] = {};

        auto stage = [&](int buf, int tstep) {
            const int k0 = tstep * 64;
#pragma unroll
            for (int c = 0; c < 4; ++c) {
                int p = t + 256 * c;
                int row = p >> 3, s = p & 7, kc = s ^ (row & 7);
                GLOAD16(ab + (size_t)(bm * 128 + row) * EMB + k0 + kc * 8, As0 + buf * 8192 + p * 8);
            }
#pragma unroll
            for (int c = 0; c < 2; ++c) {
                int p = t + 256 * c;
                int row = p >> 3, s = p & 7, kc = s ^ (row & 7);
                GLOAD16(Bt + (size_t)(bn * 64 + row) * EMB + k0 + kc * 8, Bs0 + buf * 4096 + p * 8);
            }
        };
        auto compute = [&](int cur) {
            const unsigned short* Ab = As0 + cur * 8192;
            const unsigned short* Bb = Bs0 + cur * 4096;
#pragma unroll
            for (int kk = 0; kk < 2; ++kk) {
                const int kc = kk * 4 + grp;
                bf16x8 af[4], bfr[2];
#pragma unroll
                for (int f = 0; f < 4; ++f) {
                    int mrow = wm * 64 + f * 16 + col16;
                    short8 ra = *(const short8*)(Ab + (mrow * 8 + (kc ^ (mrow & 7))) * 8);
                    af[f] = __builtin_bit_cast(bf16x8, ra);
                }
#pragma unroll
                for (int f = 0; f < 2; ++f) {
                    int nrow = wn * 32 + f * 16 + col16;
                    short8 rb = *(const short8*)(Bb + (nrow * 8 + (kc ^ (nrow & 7))) * 8);
                    bfr[f] = __builtin_bit_cast(bf16x8, rb);
                }
#pragma unroll
                for (int fi = 0; fi < 4; ++fi)
#pragma unroll
                    for (int fj = 0; fj < 2; ++fj)
                        acc[fi][fj] = __builtin_amdgcn_mfma_f32_16x16x32_bf16(af[fi], bfr[fj], acc[fi][fj], 0, 0, 0);
            }
        };

        stage(0, 0);
        stage(1, 1);
#pragma unroll 2
        for (int ts = 0; ts < 14; ++ts) {
            const int cur = ts & 1;
            asm volatile("s_waitcnt vmcnt(6)" ::: "memory");
            __builtin_amdgcn_s_barrier();
            compute(cur);
            __builtin_amdgcn_s_barrier();
            stage(cur, ts + 2);
        }
        asm volatile("s_waitcnt vmcnt(6)" ::: "memory");
        __builtin_amdgcn_s_barrier();
        compute(0);
        asm volatile("s_waitcnt vmcnt(0)" ::: "memory");
        __builtin_amdgcn_s_barrier();
        compute(1);

#pragma unroll
        for (int fi = 0; fi < 4; ++fi) {
            const int row0 = bm * 128 + wm * 64 + fi * 16 + grp * 4;
#pragma unroll
            for (int fj = 0; fj < 2; ++fj) {
                const int col = bn * 64 + wn * 32 + fj * 16 + col16;
                const float bvv = bo[col];
#pragma unroll
                for (int r = 0; r < 4; ++r)
                    Cout[(size_t)(row0 + r) * EMB + col] = acc[fi][fj][r] + bvv;
            }
        }
    }
}

// ================================================================ fallback kernels (R10, verbatim)
__global__ __launch_bounds__(256) void convert_all(const float* __restrict__ x,
                                                   const float* __restrict__ W0,
                                                   const float* __restrict__ W1,
                                                   const float* __restrict__ W2,
                                                   const float* __restrict__ W3,
                                                   ushort4* __restrict__ xb,
                                                   unsigned short* __restrict__ wt) {
    __shared__ float tile[64][65];
    const int t = threadIdx.x;
    if (blockIdx.x < 1024) {
        const int bx = blockIdx.x;
        const int w = bx >> 8, rem = bx & 255;
        const int k0 = (rem >> 4) * 64, n0 = (rem & 15) * 64;
        const float* W = (w == 0) ? W0 : (w == 1) ? W1 : (w == 2) ? W2 : W3;
        unsigned short* dst = wt + (size_t)w * (1u << 20);
        for (int i = t; i < 4096; i += 256) {
            int r = i >> 6, c = i & 63;
            tile[r][c] = W[(size_t)(k0 + r) * EMB + n0 + c];
        }
        __syncthreads();
        for (int i = t; i < 4096; i += 256) {
            int r = i >> 6, c = i & 63;
            dst[(size_t)(n0 + r) * EMB + k0 + c] = f2bf(tile[c][r]);
        }
    } else {
        const int n4 = S_LEN * EMB / 4;
        const float4* in = (const float4*)x;
        for (int i = (blockIdx.x - 1024) * 256 + t; i < n4; i += 2048 * 256) {
            float4 v = in[i];
            ushort4 o;
            o.x = f2bf(v.x); o.y = f2bf(v.y); o.z = f2bf(v.z); o.w = f2bf(v.w);
            xb[i] = o;
        }
    }
}

__global__ __launch_bounds__(256) void gemm_qkv(const unsigned short* __restrict__ A,
                                                const unsigned short* __restrict__ Bt,
                                                const float* __restrict__ bq,
                                                const float* __restrict__ bk,
                                                const float* __restrict__ bv,
                                                unsigned short* __restrict__ qb,
                                                unsigned short* __restrict__ kb,
                                                unsigned short* __restrict__ vb,
                                                unsigned short* __restrict__ vtg) {
    __shared__ unsigned short As[2][128 * 64];
    __shared__ unsigned short Bs[2][128 * 64];
    const int t = threadIdx.x;
    const int lane = t & 63;
    const int wave = t >> 6;
    const int wm = wave >> 1, wn = wave & 1;
    const int col16 = lane & 15, grp = lane >> 4;
    const int xcd = blockIdx.x & 7;
    const int li  = blockIdx.x >> 3;
    const int bn  = li >> 2;
    const int bm  = xcd * 4 + (li & 3);
    const int sel = bn >> 3, bn_l = bn & 7;
    const float* bias = (sel == 0) ? bq : (sel == 1) ? bk : bv;
    unsigned short* out = (sel == 0) ? qb : (sel == 1) ? kb : vb;

    f32x4 acc[4][4] = {};

    auto stage = [&](int buf, int tstep) {
        const int k0 = tstep * 64;
#pragma unroll
        for (int c = 0; c < 4; ++c) {
            int p = t + 256 * c;
            int row = p >> 3, s = p & 7, kc = s ^ (row & 7);
            GLOAD16(A + (size_t)(bm * 128 + row) * EMB + k0 + kc * 8, &As[buf][p * 8]);
        }
#pragma unroll
        for (int c = 0; c < 4; ++c) {
            int p = t + 256 * c;
            int row = p >> 3, s = p & 7, kc = s ^ (row & 7);
            GLOAD16(Bt + (size_t)(bn * 128 + row) * EMB + k0 + kc * 8, &Bs[buf][p * 8]);
        }
    };

    auto compute = [&](int cur) {
        const unsigned short* Ab = As[cur];
        const unsigned short* Bb = Bs[cur];
#pragma unroll
        for (int kk = 0; kk < 2; ++kk) {
            const int kc = kk * 4 + grp;
            bf16x8 af[4], bfr[4];
#pragma unroll
            for (int f = 0; f < 4; ++f) {
                int mrow = wm * 64 + f * 16 + col16;
                short8 ra = *(const short8*)(Ab + (mrow * 8 + (kc ^ (mrow & 7))) * 8);
                af[f] = __builtin_bit_cast(bf16x8, ra);
                int nrow = wn * 64 + f * 16 + col16;
                short8 rb = *(const short8*)(Bb + (nrow * 8 + (kc ^ (nrow & 7))) * 8);
                bfr[f] = __builtin_bit_cast(bf16x8, rb);
            }
#pragma unroll
            for (int fi = 0; fi < 4; ++fi)
#pragma unroll
                for (int fj = 0; fj < 4; ++fj)
                    acc[fi][fj] = __builtin_amdgcn_mfma_f32_16x16x32_bf16(af[fi], bfr[fj], acc[fi][fj], 0, 0, 0);
        }
    };

    stage(0, 0);
    stage(1, 1);

#pragma unroll 2
    for (int tstep = 0; tstep < 14; ++tstep) {
        const int cur = tstep & 1;
        asm volatile("s_waitcnt vmcnt(8)" ::: "memory");
        __builtin_amdgcn_s_barrier();
        compute(cur);
        __builtin_amdgcn_s_barrier();
        stage(cur, tstep + 2);
    }
    asm volatile("s_waitcnt vmcnt(8)" ::: "memory");
    __builtin_amdgcn_s_barrier();
    compute(0);
    asm volatile("s_waitcnt vmcnt(0)" ::: "memory");
    __builtin_amdgcn_s_barrier();
    compute(1);

#pragma unroll
    for (int fi = 0; fi < 4; ++fi) {
        const int row0 = bm * 128 + wm * 64 + fi * 16 + grp * 4;
#pragma unroll
        for (int fj = 0; fj < 4; ++fj) {
            const int col = bn_l * 128 + wn * 64 + fj * 16 + col16;
            const float bvv = bias[col];
#pragma unroll
            for (int r = 0; r < 4; ++r)
                out[(size_t)(row0 + r) * EMB + col] = f2bf(acc[fi][fj][r] + bvv);
        }
    }

    if (sel == 2) {
        __syncthreads();
        unsigned short* T = &As[0][0];
#pragma unroll
        for (int fi = 0; fi < 4; ++fi) {
            const int row_l = wm * 64 + fi * 16 + grp * 4;
#pragma unroll
            for (int fj = 0; fj < 4; ++fj) {
                const int col_l = wn * 64 + fj * 16 + col16;
                const float bvv = bias[bn_l * 128 + col_l];
#pragma unroll
                for (int r = 0; r < 4; ++r)
                    T[col_l * 128 + ((row_l + r) ^ ((col_l & 15) << 3))] = f2bf(acc[fi][fj][r] + bvv);
            }
        }
        __syncthreads();
#pragma unroll
        for (int c = 0; c < 8; ++c) {
            int q = t + 256 * c;
            int col = q >> 4, sc = q & 15, s0 = sc * 8;
            short8 v = *(const short8*)(T + col * 128 + (s0 ^ ((col & 15) << 3)));
            *(short8*)(vtg + (size_t)(bn_l * 128 + col) * S_LEN + bm * 128 + s0) = v;
        }
    }
}

__global__ __launch_bounds__(256) void gemm_out(const unsigned short* __restrict__ A,
                                                const unsigned short* __restrict__ Bt,
                                                const float* __restrict__ bias,
                                                float* __restrict__ Cout) {
    __shared__ unsigned short As[2][128 * 64];
    __shared__ unsigned short Bs[2][64 * 64];
    const int t = threadIdx.x;
    const int lane = t & 63;
    const int wave = t >> 6;
    const int wm = wave >> 1, wn = wave & 1;
    const int col16 = lane & 15, grp = lane >> 4;
    const int xcd = blockIdx.x & 7;
    const int li  = blockIdx.x >> 3;
    const int bn  = li >> 2;
    const int bm  = xcd * 4 + (li & 3);

    f32x4 acc[4][2] = {};

    auto stage = [&](int buf, int tstep) {
        const int k0 = tstep * 64;
#pragma unroll
        for (int c = 0; c < 4; ++c) {
            int p = t + 256 * c;
            int row = p >> 3, s = p & 7, kc = s ^ (row & 7);
            GLOAD16(A + (size_t)(bm * 128 + row) * EMB + k0 + kc * 8, &As[buf][p * 8]);
        }
#pragma unroll
        for (int c = 0; c < 2; ++c) {
            int p = t + 256 * c;
            int row = p >> 3, s = p & 7, kc = s ^ (row & 7);
            GLOAD16(Bt + (size_t)(bn * 64 + row) * EMB + k0 + kc * 8, &Bs[buf][p * 8]);
        }
    };

    auto compute = [&](int cur) {
        const unsigned short* Ab = As[cur];
        const unsigned short* Bb = Bs[cur];
#pragma unroll
        for (int kk = 0; kk < 2; ++kk) {
            const int kc = kk * 4 + grp;
            bf16x8 af[4], bfr[2];
#pragma unroll
            for (int f = 0; f < 4; ++f) {
                int mrow = wm * 64 + f * 16 + col16;
                short8 ra = *(const short8*)(Ab + (mrow * 8 + (kc ^ (mrow & 7))) * 8);
                af[f] = __builtin_bit_cast(bf16x8, ra);
            }
#pragma unroll
            for (int f = 0; f < 2; ++f) {
                int nrow = wn * 32 + f * 16 + col16;
                short8 rb = *(const short8*)(Bb + (nrow * 8 + (kc ^ (nrow & 7))) * 8);
                bfr[f] = __builtin_bit_cast(bf16x8, rb);
            }
#pragma unroll
            for (int fi = 0; fi < 4; ++fi)
#pragma unroll
                for (int fj = 0; fj < 2; ++fj)
                    acc[fi][fj] = __builtin_amdgcn_mfma_f32_16x16x32_bf16(af[fi], bfr[fj], acc[fi][fj], 0, 0, 0);
        }
    };

    stage(0, 0);
    stage(1, 1);

#pragma unroll 2
    for (int tstep = 0; tstep < 14; ++tstep) {
        const int cur = tstep & 1;
        asm volatile("s_waitcnt vmcnt(6)" ::: "memory");
        __builtin_amdgcn_s_barrier();
        compute(cur);
        __builtin_amdgcn_s_barrier();
        stage(cur, tstep + 2);
    }
    asm volatile("s_waitcnt vmcnt(6)" ::: "memory");
    __builtin_amdgcn_s_barrier();
    compute(0);
    asm volatile("s_waitcnt vmcnt(0)" ::: "memory");
    __builtin_amdgcn_s_barrier();
    compute(1);

#pragma unroll
    for (int fi = 0; fi < 4; ++fi) {
        const int row0 = bm * 128 + wm * 64 + fi * 16 + grp * 4;
#pragma unroll
        for (int fj = 0; fj < 2; ++fj) {
            const int col = bn * 64 + wn * 32 + fj * 16 + col16;
            const float bvv = bias[col];
#pragma unroll
            for (int r = 0; r < 4; ++r)
                Cout[(size_t)(row0 + r) * EMB + col] = acc[fi][fj][r] + bvv;
        }
    }
}

__global__ __launch_bounds__(256) void attn_fused(const unsigned short* __restrict__ qb,
                                                  const unsigned short* __restrict__ kb,
                                                  const unsigned short* __restrict__ vb,
                                                  const unsigned short* __restrict__ vtg,
                                                  unsigned short* __restrict__ ab,
                                                  float* __restrict__ o_part,
                                                  float* __restrict__ m_l) {
    __shared__ __align__(16) char smem[43072];
    const int t = threadIdx.x;
    const int lane = t & 63, wave = t >> 6;

    if (blockIdx.x < 1024) {
        unsigned short* Qs  = (unsigned short*)smem;
        unsigned short* Ks  = Qs + 64 * 64;
        unsigned short* Vts = Ks + 80 * 64;
        unsigned short* Ps  = Vts + 64 * 64;
        float* Pg = (float*)(Ps + 64 * 64);
        float* Vg = Pg + 64 * 9;

        const int col16 = lane & 15, grp = lane >> 4;
        const int h = blockIdx.x >> 6, b = blockIdx.x & 63;
        const int bc = h * 64;

#pragma unroll
        for (int c = 0; c < 2; ++c) {
            int p = t + 256 * c, row = p >> 3, s = p & 7, kc = s ^ (row & 7);
            GLOAD16(qb + (size_t)(b * 64 + row) * EMB + bc + kc * 8, Qs + p * 8);
        }
#pragma unroll
        for (int c = 0; c < 3; ++c) {
            int p = t + 256 * c;
            if (p < 576) {
                int row = p >> 3, s = p & 7, kc = s ^ (row & 7);
                int srow = (row < 64) ? (b * 64 + row) : GPOS[row - 64];
                GLOAD16(kb + (size_t)srow * EMB + bc + kc * 8, Ks + p * 8);
            }
        }
        if (t < 64) {
            short8 z = {};
            *(short8*)(Ks + (576 + t) * 8) = z;
        }
#pragma unroll
        for (int c = 0; c < 2; ++c) {
            int p = t + 256 * c, row = p >> 3, s = p & 7, kc = s ^ (row & 7);
            GLOAD16(vtg + (size_t)(bc + row) * S_LEN + b * 64 + kc * 8, Vts + p * 8);
        }
        for (int i = t; i < 512; i += 256) {
            int g = i >> 6, d = i & 63;
            Vg[g * 64 + d] = bf2f(vb[(size_t)GPOS[g] * EMB + bc + d]);
        }
        asm volatile("s_waitcnt vmcnt(0)" ::: "memory");
        __syncthreads();

        f32x4 sc[5] = {};
        const int arow = wave * 16 + col16;
#pragma unroll
        for (int kk = 0; kk < 2; ++kk) {
            const int kc = kk * 4 + grp;
            short8 ra = *(const short8*)(Qs + (arow * 8 + (kc ^ (arow & 7))) * 8);
            bf16x8 af = __builtin_bit_cast(bf16x8, ra);
#pragma unroll
            for (int n = 0; n < 5; ++n) {
                const int brow = n * 16 + col16;
                short8 rb = *(const short8*)(Ks + (brow * 8 + (kc ^ (brow & 7))) * 8);
                sc[n] = __builtin_amdgcn_mfma_f32_16x16x32_bf16(af, __builtin_bit_cast(bf16x8, rb), sc[n], 0, 0, 0);
            }
        }

        const bool valid4 = (col16 < 8) && ((GPOS[col16] >> 6) != b);
#pragma unroll
        for (int r = 0; r < 4; ++r) {
            const int row = wave * 16 + grp * 4 + r;
            float s[5];
#pragma unroll
            for (int n = 0; n < 4; ++n) s[n] = sc[n][r] * 0.125f;
            s[4] = valid4 ? sc[4][r] * 0.125f : -1e30f;
            float m = fmaxf(fmaxf(fmaxf(s[0], s[1]), fmaxf(s[2], s[3])), s[4]);
#pragma unroll
            for (int off = 1; off < 16; off <<= 1) m = fmaxf(m, __shfl_xor(m, off));
            float e[5], l = 0.f;
#pragma unroll
            for (int n = 0; n < 5; ++n) { e[n] = __expf(s[n] - m); l += e[n]; }
#pragma unroll
            for (int off = 1; off < 16; off <<= 1) l += __shfl_xor(l, off);
            const float inv = 1.f / l;
#pragma unroll
            for (int n = 0; n < 4; ++n) {
                const int col = n * 16 + col16;
                const int kc = col >> 3;
                Ps[(row * 8 + (kc ^ (row & 7))) * 8 + (col & 7)] = f2bf(e[n] * inv);
            }
            if (col16 < 8) Pg[row * 9 + col16] = e[4] * inv;
        }
        __syncthreads();

        f32x4 oa[4] = {};
#pragma unroll
        for (int kk = 0; kk < 2; ++kk) {
            const int kc = kk * 4 + grp;
            short8 ra = *(const short8*)(Ps + (arow * 8 + (kc ^ (arow & 7))) * 8);
            bf16x8 af = __builtin_bit_cast(bf16x8, ra);
#pragma unroll
            for (int n = 0; n < 4; ++n) {
                const int drow = n * 16 + col16;
                short8 rb = *(const short8*)(Vts + (drow * 8 + (kc ^ (drow & 7))) * 8);
                oa[n] = __builtin_amdgcn_mfma_f32_16x16x32_bf16(af, __builtin_bit_cast(bf16x8, rb), oa[n], 0, 0, 0);
            }
        }

        float pgr[4][8];
#pragma unroll
        for (int r = 0; r < 4; ++r) {
            const int row = wave * 16 + grp * 4 + r;
#pragma unroll
            for (int g = 0; g < 8; ++g) pgr[r][g] = Pg[row * 9 + g];
        }
#pragma unroll
        for (int n = 0; n < 4; ++n) {
            const int d = n * 16 + col16;
#pragma unroll
            for (int g = 0; g < 8; ++g) {
                const float vg = Vg[g * 64 + d];
#pragma unroll
                for (int r = 0; r < 4; ++r) oa[n][r] += pgr[r][g] * vg;
            }
        }

#pragma unroll
        for (int n = 0; n < 4; ++n) {
            const int d = n * 16 + col16;
#pragma unroll
            for (int r = 0; r < 4; ++r) {
                const int row = wave * 16 + grp * 4 + r;
                ab[(size_t)(b * 64 + row) * EMB + bc + d] = f2bf(oa[n][r]);
            }
        }
    } else {
        float* Qsf = (float*)smem;
        unsigned short* Vs = (unsigned short*)(smem + 2048);
        float* Ps = (float*)(smem + 2048 + 32768);
        float* mfin = Ps + 8 * 256;
        float* lfin = mfin + 8;

        const int bx = blockIdx.x - 1024;
        const int h = bx >> 4;
        const int ch = bx & (NCHUNK - 1);
        const int bc = h * 64;
        const int k0 = ch * GCHUNK;

        for (int i = t; i < 512; i += 256) {
            int r = i >> 6, d = i & 63;
            Qsf[r * 64 + d] = bf2f(qb[(size_t)GPOS[r] * EMB + bc + d]);
        }
        {
            const unsigned short* vrow = vb + (size_t)(k0 + t) * EMB + bc;
#pragma unroll
            for (int c = 0; c < 8; ++c) {
                short8 vv = *(const short8*)(vrow + c * 8);
                *(short8*)(&Vs[t * 64 + (c ^ (t & 7)) * 8]) = vv;
            }
        }
        float kf[64];
        {
            const unsigned short* krow = kb + (size_t)(k0 + t) * EMB + bc;
#pragma unroll
            for (int c = 0; c < 8; ++c) {
                short8 kv = *(const short8*)(krow + c * 8);
#pragma unroll
                for (int j = 0; j < 8; ++j) kf[c * 8 + j] = bf2f((unsigned short)kv[j]);
            }
        }
        __syncthreads();

#pragma unroll
        for (int r = 0; r < 8; ++r) {
            float a0 = 0.f, a1 = 0.f, a2 = 0.f, a3 = 0.f;
#pragma unroll
            for (int c4 = 0; c4 < 16; ++c4) {
                f32x4 q = *(const f32x4*)&Qsf[r * 64 + c4 * 4];
                a0 += q.x * kf[c4 * 4 + 0];
                a1 += q.y * kf[c4 * 4 + 1];
                a2 += q.z * kf[c4 * 4 + 2];
                a3 += q.w * kf[c4 * 4 + 3];
            }
            Ps[r * 256 + t] = (a0 + a1 + a2 + a3) * 0.125f;
        }
        __syncthreads();

#pragma unroll
        for (int rr = 0; rr < 2; ++rr) {
            const int r = wave * 2 + rr;
            float v0 = Ps[r * 256 + lane], v1 = Ps[r * 256 + lane + 64],
                  v2 = Ps[r * 256 + lane + 128], v3 = Ps[r * 256 + lane + 192];
            float m = fmaxf(fmaxf(v0, v1), fmaxf(v2, v3));
#pragma unroll
            for (int off = 1; off < 64; off <<= 1) m = fmaxf(m, __shfl_xor(m, off));
            float e0 = __expf(v0 - m), e1 = __expf(v1 - m), e2 = __expf(v2 - m), e3 = __expf(v3 - m);
            float l = e0 + e1 + e2 + e3;
#pragma unroll
            for (int off = 1; off < 64; off <<= 1) l += __shfl_xor(l, off);
            Ps[r * 256 + lane] = e0; Ps[r * 256 + lane + 64] = e1;
            Ps[r * 256 + lane + 128] = e2; Ps[r * 256 + lane + 192] = e3;
            if (lane == 0) { mfin[r] = m; lfin[r] = l; }
        }
        __syncthreads();

        const int r = t >> 5;
        const int d0 = (t & 31) * 2;
        const int cc = d0 >> 3, ee = d0 & 7;
        float acc0 = 0.f, acc1 = 0.f;
        for (int k = 0; k < GCHUNK; k += 4) {
            f32x4 p = *(const f32x4*)&Ps[r * 256 + k];
#pragma unroll
            for (int j = 0; j < 4; ++j) {
                unsigned int vv = *(const unsigned int*)&Vs[(k + j) * 64 + ((cc ^ ((k + j) & 7)) << 3) + ee];
                acc0 += p[j] * bf2f((unsigned short)(vv & 0xffff));
                acc1 += p[j] * bf2f((unsigned short)(vv >> 16));
            }
        }
        const int rowg = h * 8 + r;
        float* od = o_part + ((size_t)rowg * NCHUNK + ch) * 64 + d0;
        od[0] = acc0; od[1] = acc1;
        if ((t & 31) == 0) {
            m_l[((size_t)rowg * NCHUNK + ch) * 2 + 0] = mfin[r];
            m_l[((size_t)rowg * NCHUNK + ch) * 2 + 1] = lfin[r];
        }
    }
}

__global__ __launch_bounds__(256) void attn_gcomb(const float* __restrict__ o_part,
                                                  const float* __restrict__ m_l,
                                                  unsigned short* __restrict__ ab) {
    const int gid = blockIdx.x * 256 + threadIdx.x;
    const int row = gid >> 6, d = gid & 63;
    float M = -1e30f;
#pragma unroll
    for (int c = 0; c < NCHUNK; ++c) M = fmaxf(M, m_l[((size_t)row * NCHUNK + c) * 2]);
    float L = 0.f, o = 0.f;
#pragma unroll
    for (int c = 0; c < NCHUNK; ++c) {
        float w = __expf(m_l[((size_t)row * NCHUNK + c) * 2] - M);
        L += m_l[((size_t)row * NCHUNK + c) * 2 + 1] * w;
        o += o_part[((size_t)row * NCHUNK + c) * 64 + d] * w;
    }
    const int h = row >> 3, gi = row & 7;
    ab[(size_t)GPOS[gi] * EMB + h * 64 + d] = f2bf(o / L);
}

// ================================================================ launch
extern "C" void kernel_launch(void* const* d_in, const int* in_sizes, int n_in,
                              void* d_out, int out_size, void* d_ws, size_t ws_size,
                              hipStream_t stream) {
    const float* x  = (const float*)d_in[0];
    const float* Wq = (const float*)d_in[1];
    const float* bq = (const float*)d_in[2];
    const float* Wk = (const float*)d_in[3];
    const float* bk = (const float*)d_in[4];
    const float* Wv = (const float*)d_in[5];
    const float* bv = (const float*)d_in[6];
    const float* Wo = (const float*)d_in[7];
    const float* bo = (const float*)d_in[8];

    char* ws = (char*)d_ws;
    unsigned short* xb = (unsigned short*)ws;
    unsigned short* wt = (unsigned short*)(ws + (8u << 20));
    unsigned short* qb = (unsigned short*)(ws + (16u << 20));
    unsigned short* kb = (unsigned short*)(ws + (24u << 20));
    unsigned short* vb = (unsigned short*)(ws + (32u << 20));
    unsigned short* ab = xb;

    float* o_part = (float*)d_out;
    float* m_l    = (float*)d_out + 128 * NCHUNK * 64;
    unsigned short* vtg = (unsigned short*)((char*)d_out + (4u << 20));
    unsigned int* ctrs  = (unsigned int*)((char*)d_out + (12u << 20));
    float* Cout = (float*)d_out;

    // pick cooperative grid from the runtime's own occupancy model (host-side, capture-safe)
    int maxb = 0;
    hipError_t qerr = hipOccupancyMaxActiveBlocksPerMultiprocessor(&maxb, (const void*)mega, 256, 0);
    int numCU = 256;
    {
        int dev = 0;
        if (hipGetDevice(&dev) == hipSuccess)
            hipDeviceGetAttribute(&numCU, hipDeviceAttributeMultiprocessorCount, dev);
    }
    bool launched = false;
    if (qerr == hipSuccess && maxb > 0) {
        int grid = maxb * numCU;
        if (grid > 512) grid = 512;
        void* kargs[] = {
            (void*)&x, (void*)&Wq, (void*)&bq, (void*)&Wk, (void*)&bk,
            (void*)&Wv, (void*)&bv, (void*)&Wo, (void*)&bo,
            (void*)&xb, (void*)&wt, (void*)&qb, (void*)&kb, (void*)&vb, (void*)&vtg,
            (void*)&o_part, (void*)&m_l, (void*)&Cout, (void*)&ctrs
        };
        launched = (hipLaunchCooperativeKernel((const void*)mega, dim3(grid), dim3(256),
                                               kargs, 0, stream) == hipSuccess);
    }

    if (!launched) {  // R10 fallback path (identical output)
        convert_all<<<3072, 256, 0, stream>>>(x, Wq, Wk, Wv, Wo, (ushort4*)xb, wt);
        gemm_qkv<<<(S_LEN / 128) * 24, 256, 0, stream>>>(xb, wt, bq, bk, bv, qb, kb, vb, vtg);
        attn_fused<<<1024 + NHEAD * NCHUNK, 256, 0, stream>>>(qb, kb, vb, vtg, ab, o_part, m_l);
        attn_gcomb<<<(128 * 64) / 256, 256, 0, stream>>>(o_part, m_l, ab);
        gemm_out<<<(S_LEN / 128) * 16, 256, 0, stream>>>(ab, wt + (3u << 20), bo, Cout);
    }
}

// Round 14
// 107.538 us; speedup vs baseline: 2.4956x; 2.4956x over previous
//
#include <hip/hip_runtime.h>

typedef __attribute__((ext_vector_type(8))) short short8;
typedef __attribute__((ext_vector_type(8))) __bf16 bf16x8;
typedef __attribute__((ext_vector_type(4))) float f32x4;

#define S_LEN 4096
#define EMB   1024
#define NHEAD 16
#define GCHUNK 256
#define NCHUNK (S_LEN / GCHUNK)   // 16

__constant__ int GPOS[8] = {0, 585, 1170, 1755, 2340, 2925, 3510, 4095};

__device__ __forceinline__ unsigned short f2bf(float f) {
    unsigned int u = __float_as_uint(f);
    u += 0x7fffu + ((u >> 16) & 1u);
    return (unsigned short)(u >> 16);
}
__device__ __forceinline__ float bf2f(unsigned short s) {
    return __uint_as_float(((unsigned int)s) << 16);
}
#define GLOAD16(src, dst) __builtin_amdgcn_global_load_lds( \
    (const __attribute__((address_space(1))) void*)(src),    \
    (__attribute__((address_space(3))) void*)(dst), 16, 0, 0)

// ---------------------------------------------------------------- converts (merged) + counter init
__global__ __launch_bounds__(256) void convert_all(const float* __restrict__ x,
                                                   const float* __restrict__ W0,
                                                   const float* __restrict__ W1,
                                                   const float* __restrict__ W2,
                                                   const float* __restrict__ W3,
                                                   ushort4* __restrict__ xb,
                                                   unsigned short* __restrict__ wt,
                                                   unsigned int* __restrict__ ctrs) {
    __shared__ float tile[64][65];
    const int t = threadIdx.x;
    if (blockIdx.x == 0 && t < NHEAD) ctrs[t] = 0u;   // re-zeroed every call (graph-replay safe)
    if (blockIdx.x < 1024) {
        const int bx = blockIdx.x;
        const int w = bx >> 8, rem = bx & 255;
        const int k0 = (rem >> 4) * 64, n0 = (rem & 15) * 64;
        const float* W = (w == 0) ? W0 : (w == 1) ? W1 : (w == 2) ? W2 : W3;
        unsigned short* dst = wt + (size_t)w * (1u << 20);
        for (int i = t; i < 4096; i += 256) {
            int r = i >> 6, c = i & 63;
            tile[r][c] = W[(size_t)(k0 + r) * EMB + n0 + c];
        }
        __syncthreads();
        for (int i = t; i < 4096; i += 256) {
            int r = i >> 6, c = i & 63;
            dst[(size_t)(n0 + r) * EMB + k0 + c] = f2bf(tile[c][r]);
        }
    } else {
        const int n4 = S_LEN * EMB / 4;
        const float4* in = (const float4*)x;
        for (int i = (blockIdx.x - 1024) * 256 + t; i < n4; i += 2048 * 256) {
            float4 v = in[i];
            ushort4 o;
            o.x = f2bf(v.x); o.y = f2bf(v.y); o.z = f2bf(v.z); o.w = f2bf(v.w);
            xb[i] = o;
        }
    }
}

// ---------------------------------------------------------------- fused QKV GEMM (R10-proven)
__global__ __launch_bounds__(256) void gemm_qkv(const unsigned short* __restrict__ A,
                                                const unsigned short* __restrict__ Bt,
                                                const float* __restrict__ bq,
                                                const float* __restrict__ bk,
                                                const float* __restrict__ bv,
                                                unsigned short* __restrict__ qb,
                                                unsigned short* __restrict__ kb,
                                                unsigned short* __restrict__ vb,
                                                unsigned short* __restrict__ vtg) {
    __shared__ unsigned short As[2][128 * 64];
    __shared__ unsigned short Bs[2][128 * 64];
    const int t = threadIdx.x;
    const int lane = t & 63;
    const int wave = t >> 6;
    const int wm = wave >> 1, wn = wave & 1;
    const int col16 = lane & 15, grp = lane >> 4;
    const int xcd = blockIdx.x & 7;
    const int li  = blockIdx.x >> 3;
    const int bn  = li >> 2;
    const int bm  = xcd * 4 + (li & 3);
    const int sel = bn >> 3, bn_l = bn & 7;
    const float* bias = (sel == 0) ? bq : (sel == 1) ? bk : bv;
    unsigned short* out = (sel == 0) ? qb : (sel == 1) ? kb : vb;

    f32x4 acc[4][4] = {};

    auto stage = [&](int buf, int tstep) {
        const int k0 = tstep * 64;
#pragma unroll
        for (int c = 0; c < 4; ++c) {
            int p = t + 256 * c;
            int row = p >> 3, s = p & 7, kc = s ^ (row & 7);
            GLOAD16(A + (size_t)(bm * 128 + row) * EMB + k0 + kc * 8, &As[buf][p * 8]);
        }
#pragma unroll
        for (int c = 0; c < 4; ++c) {
            int p = t + 256 * c;
            int row = p >> 3, s = p & 7, kc = s ^ (row & 7);
            GLOAD16(Bt + (size_t)(bn * 128 + row) * EMB + k0 + kc * 8, &Bs[buf][p * 8]);
        }
    };

    auto compute = [&](int cur) {
        const unsigned short* Ab = As[cur];
        const unsigned short* Bb = Bs[cur];
#pragma unroll
        for (int kk = 0; kk < 2; ++kk) {
            const int kc = kk * 4 + grp;
            bf16x8 af[4], bfr[4];
#pragma unroll
            for (int f = 0; f < 4; ++f) {
                int mrow = wm * 64 + f * 16 + col16;
                short8 ra = *(const short8*)(Ab + (mrow * 8 + (kc ^ (mrow & 7))) * 8);
                af[f] = __builtin_bit_cast(bf16x8, ra);
                int nrow = wn * 64 + f * 16 + col16;
                short8 rb = *(const short8*)(Bb + (nrow * 8 + (kc ^ (nrow & 7))) * 8);
                bfr[f] = __builtin_bit_cast(bf16x8, rb);
            }
#pragma unroll
            for (int fi = 0; fi < 4; ++fi)
#pragma unroll
                for (int fj = 0; fj < 4; ++fj)
                    acc[fi][fj] = __builtin_amdgcn_mfma_f32_16x16x32_bf16(af[fi], bfr[fj], acc[fi][fj], 0, 0, 0);
        }
    };

    stage(0, 0);
    stage(1, 1);

#pragma unroll 2
    for (int tstep = 0; tstep < 14; ++tstep) {
        const int cur = tstep & 1;
        asm volatile("s_waitcnt vmcnt(8)" ::: "memory");
        __builtin_amdgcn_s_barrier();
        compute(cur);
        __builtin_amdgcn_s_barrier();
        stage(cur, tstep + 2);
    }
    asm volatile("s_waitcnt vmcnt(8)" ::: "memory");
    __builtin_amdgcn_s_barrier();
    compute(0);
    asm volatile("s_waitcnt vmcnt(0)" ::: "memory");
    __builtin_amdgcn_s_barrier();
    compute(1);

#pragma unroll
    for (int fi = 0; fi < 4; ++fi) {
        const int row0 = bm * 128 + wm * 64 + fi * 16 + grp * 4;
#pragma unroll
        for (int fj = 0; fj < 4; ++fj) {
            const int col = bn_l * 128 + wn * 64 + fj * 16 + col16;
            const float bvv = bias[col];
#pragma unroll
            for (int r = 0; r < 4; ++r)
                out[(size_t)(row0 + r) * EMB + col] = f2bf(acc[fi][fj][r] + bvv);
        }
    }

    if (sel == 2) {
        __syncthreads();
        unsigned short* T = &As[0][0];
#pragma unroll
        for (int fi = 0; fi < 4; ++fi) {
            const int row_l = wm * 64 + fi * 16 + grp * 4;
#pragma unroll
            for (int fj = 0; fj < 4; ++fj) {
                const int col_l = wn * 64 + fj * 16 + col16;
                const float bvv = bias[bn_l * 128 + col_l];
#pragma unroll
                for (int r = 0; r < 4; ++r)
                    T[col_l * 128 + ((row_l + r) ^ ((col_l & 15) << 3))] = f2bf(acc[fi][fj][r] + bvv);
            }
        }
        __syncthreads();
#pragma unroll
        for (int c = 0; c < 8; ++c) {
            int q = t + 256 * c;
            int col = q >> 4, sc = q & 15, s0 = sc * 8;
            short8 v = *(const short8*)(T + col * 128 + (s0 ^ ((col & 15) << 3)));
            *(short8*)(vtg + (size_t)(bn_l * 128 + col) * S_LEN + bm * 128 + s0) = v;
        }
    }
}

// ---------------------------------------------------------------- output GEMM (R10-proven, 512 blocks)
__global__ __launch_bounds__(256) void gemm_out(const unsigned short* __restrict__ A,
                                                const unsigned short* __restrict__ Bt,
                                                const float* __restrict__ bias,
                                                float* __restrict__ Cout) {
    __shared__ unsigned short As[2][128 * 64];
    __shared__ unsigned short Bs[2][64 * 64];
    const int t = threadIdx.x;
    const int lane = t & 63;
    const int wave = t >> 6;
    const int wm = wave >> 1, wn = wave & 1;
    const int col16 = lane & 15, grp = lane >> 4;
    const int xcd = blockIdx.x & 7;
    const int li  = blockIdx.x >> 3;
    const int bn  = li >> 2;
    const int bm  = xcd * 4 + (li & 3);

    f32x4 acc[4][2] = {};

    auto stage = [&](int buf, int tstep) {
        const int k0 = tstep * 64;
#pragma unroll
        for (int c = 0; c < 4; ++c) {
            int p = t + 256 * c;
            int row = p >> 3, s = p & 7, kc = s ^ (row & 7);
            GLOAD16(A + (size_t)(bm * 128 + row) * EMB + k0 + kc * 8, &As[buf][p * 8]);
        }
#pragma unroll
        for (int c = 0; c < 2; ++c) {
            int p = t + 256 * c;
            int row = p >> 3, s = p & 7, kc = s ^ (row & 7);
            GLOAD16(Bt + (size_t)(bn * 64 + row) * EMB + k0 + kc * 8, &Bs[buf][p * 8]);
        }
    };

    auto compute = [&](int cur) {
        const unsigned short* Ab = As[cur];
        const unsigned short* Bb = Bs[cur];
#pragma unroll
        for (int kk = 0; kk < 2; ++kk) {
            const int kc = kk * 4 + grp;
            bf16x8 af[4], bfr[2];
#pragma unroll
            for (int f = 0; f < 4; ++f) {
                int mrow = wm * 64 + f * 16 + col16;
                short8 ra = *(const short8*)(Ab + (mrow * 8 + (kc ^ (mrow & 7))) * 8);
                af[f] = __builtin_bit_cast(bf16x8, ra);
            }
#pragma unroll
            for (int f = 0; f < 2; ++f) {
                int nrow = wn * 32 + f * 16 + col16;
                short8 rb = *(const short8*)(Bb + (nrow * 8 + (kc ^ (nrow & 7))) * 8);
                bfr[f] = __builtin_bit_cast(bf16x8, rb);
            }
#pragma unroll
            for (int fi = 0; fi < 4; ++fi)
#pragma unroll
                for (int fj = 0; fj < 2; ++fj)
                    acc[fi][fj] = __builtin_amdgcn_mfma_f32_16x16x32_bf16(af[fi], bfr[fj], acc[fi][fj], 0, 0, 0);
        }
    };

    stage(0, 0);
    stage(1, 1);

#pragma unroll 2
    for (int tstep = 0; tstep < 14; ++tstep) {
        const int cur = tstep & 1;
        asm volatile("s_waitcnt vmcnt(6)" ::: "memory");
        __builtin_amdgcn_s_barrier();
        compute(cur);
        __builtin_amdgcn_s_barrier();
        stage(cur, tstep + 2);
    }
    asm volatile("s_waitcnt vmcnt(6)" ::: "memory");
    __builtin_amdgcn_s_barrier();
    compute(0);
    asm volatile("s_waitcnt vmcnt(0)" ::: "memory");
    __builtin_amdgcn_s_barrier();
    compute(1);

#pragma unroll
    for (int fi = 0; fi < 4; ++fi) {
        const int row0 = bm * 128 + wm * 64 + fi * 16 + grp * 4;
#pragma unroll
        for (int fj = 0; fj < 2; ++fj) {
            const int col = bn * 64 + wn * 32 + fj * 16 + col16;
            const float bvv = bias[col];
#pragma unroll
            for (int r = 0; r < 4; ++r)
                Cout[(size_t)(row0 + r) * EMB + col] = acc[fi][fj][r] + bvv;
        }
    }
}

// ---------------------------------------------------------------- fused attention (+ last-arriver gcomb)
__global__ __launch_bounds__(256) void attn_fused(const unsigned short* __restrict__ qb,
                                                  const unsigned short* __restrict__ kb,
                                                  const unsigned short* __restrict__ vb,
                                                  const unsigned short* __restrict__ vtg,
                                                  unsigned short* __restrict__ ab,
                                                  float* __restrict__ o_part,
                                                  float* __restrict__ m_l,
                                                  unsigned int* __restrict__ ctrs) {
    __shared__ __align__(16) char smem[43072];
    __shared__ unsigned int lastflag;
    const int t = threadIdx.x;
    const int lane = t & 63, wave = t >> 6;

    if (blockIdx.x < 1024) {
        unsigned short* Qs  = (unsigned short*)smem;
        unsigned short* Ks  = Qs + 64 * 64;
        unsigned short* Vts = Ks + 80 * 64;
        unsigned short* Ps  = Vts + 64 * 64;
        float* Pg = (float*)(Ps + 64 * 64);
        float* Vg = Pg + 64 * 9;

        const int col16 = lane & 15, grp = lane >> 4;
        const int h = blockIdx.x >> 6, b = blockIdx.x & 63;
        const int bc = h * 64;

#pragma unroll
        for (int c = 0; c < 2; ++c) {
            int p = t + 256 * c, row = p >> 3, s = p & 7, kc = s ^ (row & 7);
            GLOAD16(qb + (size_t)(b * 64 + row) * EMB + bc + kc * 8, Qs + p * 8);
        }
#pragma unroll
        for (int c = 0; c < 3; ++c) {
            int p = t + 256 * c;
            if (p < 576) {
                int row = p >> 3, s = p & 7, kc = s ^ (row & 7);
                int srow = (row < 64) ? (b * 64 + row) : GPOS[row - 64];
                GLOAD16(kb + (size_t)srow * EMB + bc + kc * 8, Ks + p * 8);
            }
        }
        if (t < 64) {
            short8 z = {};
            *(short8*)(Ks + (576 + t) * 8) = z;
        }
#pragma unroll
        for (int c = 0; c < 2; ++c) {
            int p = t + 256 * c, row = p >> 3, s = p & 7, kc = s ^ (row & 7);
            GLOAD16(vtg + (size_t)(bc + row) * S_LEN + b * 64 + kc * 8, Vts + p * 8);
        }
        for (int i = t; i < 512; i += 256) {
            int g = i >> 6, d = i & 63;
            Vg[g * 64 + d] = bf2f(vb[(size_t)GPOS[g] * EMB + bc + d]);
        }
        asm volatile("s_waitcnt vmcnt(0)" ::: "memory");
        __syncthreads();

        f32x4 sc[5] = {};
        const int arow = wave * 16 + col16;
#pragma unroll
        for (int kk = 0; kk < 2; ++kk) {
            const int kc = kk * 4 + grp;
            short8 ra = *(const short8*)(Qs + (arow * 8 + (kc ^ (arow & 7))) * 8);
            bf16x8 af = __builtin_bit_cast(bf16x8, ra);
#pragma unroll
            for (int n = 0; n < 5; ++n) {
                const int brow = n * 16 + col16;
                short8 rb = *(const short8*)(Ks + (brow * 8 + (kc ^ (brow & 7))) * 8);
                sc[n] = __builtin_amdgcn_mfma_f32_16x16x32_bf16(af, __builtin_bit_cast(bf16x8, rb), sc[n], 0, 0, 0);
            }
        }

        const bool valid4 = (col16 < 8) && ((GPOS[col16] >> 6) != b);
#pragma unroll
        for (int r = 0; r < 4; ++r) {
            const int row = wave * 16 + grp * 4 + r;
            float s[5];
#pragma unroll
            for (int n = 0; n < 4; ++n) s[n] = sc[n][r] * 0.125f;
            s[4] = valid4 ? sc[4][r] * 0.125f : -1e30f;
            float m = fmaxf(fmaxf(fmaxf(s[0], s[1]), fmaxf(s[2], s[3])), s[4]);
#pragma unroll
            for (int off = 1; off < 16; off <<= 1) m = fmaxf(m, __shfl_xor(m, off));
            float e[5], l = 0.f;
#pragma unroll
            for (int n = 0; n < 5; ++n) { e[n] = __expf(s[n] - m); l += e[n]; }
#pragma unroll
            for (int off = 1; off < 16; off <<= 1) l += __shfl_xor(l, off);
            const float inv = 1.f / l;
#pragma unroll
            for (int n = 0; n < 4; ++n) {
                const int col = n * 16 + col16;
                const int kc = col >> 3;
                Ps[(row * 8 + (kc ^ (row & 7))) * 8 + (col & 7)] = f2bf(e[n] * inv);
            }
            if (col16 < 8) Pg[row * 9 + col16] = e[4] * inv;
        }
        __syncthreads();

        f32x4 oa[4] = {};
#pragma unroll
        for (int kk = 0; kk < 2; ++kk) {
            const int kc = kk * 4 + grp;
            short8 ra = *(const short8*)(Ps + (arow * 8 + (kc ^ (arow & 7))) * 8);
            bf16x8 af = __builtin_bit_cast(bf16x8, ra);
#pragma unroll
            for (int n = 0; n < 4; ++n) {
                const int drow = n * 16 + col16;
                short8 rb = *(const short8*)(Vts + (drow * 8 + (kc ^ (drow & 7))) * 8);
                oa[n] = __builtin_amdgcn_mfma_f32_16x16x32_bf16(af, __builtin_bit_cast(bf16x8, rb), oa[n], 0, 0, 0);
            }
        }

        float pgr[4][8];
#pragma unroll
        for (int r = 0; r < 4; ++r) {
            const int row = wave * 16 + grp * 4 + r;
#pragma unroll
            for (int g = 0; g < 8; ++g) pgr[r][g] = Pg[row * 9 + g];
        }
#pragma unroll
        for (int n = 0; n < 4; ++n) {
            const int d = n * 16 + col16;
#pragma unroll
            for (int g = 0; g < 8; ++g) {
                const float vg = Vg[g * 64 + d];
#pragma unroll
                for (int r = 0; r < 4; ++r) oa[n][r] += pgr[r][g] * vg;
            }
        }

#pragma unroll
        for (int n = 0; n < 4; ++n) {
            const int d = n * 16 + col16;
#pragma unroll
            for (int r = 0; r < 4; ++r) {
                const int row = wave * 16 + grp * 4 + r;
                ab[(size_t)(b * 64 + row) * EMB + bc + d] = f2bf(oa[n][r]);
            }
        }
    } else {
        float* Qsf = (float*)smem;
        unsigned short* Vs = (unsigned short*)(smem + 2048);
        float* Ps = (float*)(smem + 2048 + 32768);
        float* mfin = Ps + 8 * 256;
        float* lfin = mfin + 8;

        const int bx = blockIdx.x - 1024;
        const int h = bx >> 4;
        const int ch = bx & (NCHUNK - 1);
        const int bc = h * 64;
        const int k0 = ch * GCHUNK;

        for (int i = t; i < 512; i += 256) {
            int r = i >> 6, d = i & 63;
            Qsf[r * 64 + d] = bf2f(qb[(size_t)GPOS[r] * EMB + bc + d]);
        }
        {
            const unsigned short* vrow = vb + (size_t)(k0 + t) * EMB + bc;
#pragma unroll
            for (int c = 0; c < 8; ++c) {
                short8 vv = *(const short8*)(vrow + c * 8);
                *(short8*)(&Vs[t * 64 + (c ^ (t & 7)) * 8]) = vv;
            }
        }
        float kf[64];
        {
            const unsigned short* krow = kb + (size_t)(k0 + t) * EMB + bc;
#pragma unroll
            for (int c = 0; c < 8; ++c) {
                short8 kv = *(const short8*)(krow + c * 8);
#pragma unroll
                for (int j = 0; j < 8; ++j) kf[c * 8 + j] = bf2f((unsigned short)kv[j]);
            }
        }
        __syncthreads();

#pragma unroll
        for (int r = 0; r < 8; ++r) {
            float a0 = 0.f, a1 = 0.f, a2 = 0.f, a3 = 0.f;
#pragma unroll
            for (int c4 = 0; c4 < 16; ++c4) {
                f32x4 q = *(const f32x4*)&Qsf[r * 64 + c4 * 4];
                a0 += q.x * kf[c4 * 4 + 0];
                a1 += q.y * kf[c4 * 4 + 1];
                a2 += q.z * kf[c4 * 4 + 2];
                a3 += q.w * kf[c4 * 4 + 3];
            }
            Ps[r * 256 + t] = (a0 + a1 + a2 + a3) * 0.125f;
        }
        __syncthreads();

#pragma unroll
        for (int rr = 0; rr < 2; ++rr) {
            const int r = wave * 2 + rr;
            float v0 = Ps[r * 256 + lane], v1 = Ps[r * 256 + lane + 64],
                  v2 = Ps[r * 256 + lane + 128], v3 = Ps[r * 256 + lane + 192];
            float m = fmaxf(fmaxf(v0, v1), fmaxf(v2, v3));
#pragma unroll
            for (int off = 1; off < 64; off <<= 1) m = fmaxf(m, __shfl_xor(m, off));
            float e0 = __expf(v0 - m), e1 = __expf(v1 - m), e2 = __expf(v2 - m), e3 = __expf(v3 - m);
            float l = e0 + e1 + e2 + e3;
#pragma unroll
            for (int off = 1; off < 64; off <<= 1) l += __shfl_xor(l, off);
            Ps[r * 256 + lane] = e0; Ps[r * 256 + lane + 64] = e1;
            Ps[r * 256 + lane + 128] = e2; Ps[r * 256 + lane + 192] = e3;
            if (lane == 0) { mfin[r] = m; lfin[r] = l; }
        }
        __syncthreads();

        const int r = t >> 5;
        const int d0 = (t & 31) * 2;
        const int cc = d0 >> 3, ee = d0 & 7;
        float acc0 = 0.f, acc1 = 0.f;
        for (int k = 0; k < GCHUNK; k += 4) {
            f32x4 p = *(const f32x4*)&Ps[r * 256 + k];
#pragma unroll
            for (int j = 0; j < 4; ++j) {
                unsigned int vv = *(const unsigned int*)&Vs[(k + j) * 64 + ((cc ^ ((k + j) & 7)) << 3) + ee];
                acc0 += p[j] * bf2f((unsigned short)(vv & 0xffff));
                acc1 += p[j] * bf2f((unsigned short)(vv >> 16));
            }
        }
        const int rowg = h * 8 + r;
        float* od = o_part + ((size_t)rowg * NCHUNK + ch) * 64 + d0;
        od[0] = acc0; od[1] = acc1;
        if ((t & 31) == 0) {
            m_l[((size_t)rowg * NCHUNK + ch) * 2 + 0] = mfin[r];
            m_l[((size_t)rowg * NCHUNK + ch) * 2 + 1] = lfin[r];
        }

        // ---- last-arriver combine for head h (replaces attn_gcomb kernel)
        __threadfence();              // release this block's partials (device scope)
        __syncthreads();
        if (t == 0) lastflag = (atomicAdd(&ctrs[h], 1u) == NCHUNK - 1u);
        __syncthreads();
        if (lastflag) {
            __threadfence();          // acquire: all 16 chunk-blocks' partials visible
            for (int i = t; i < 8 * 64; i += 256) {
                const int gr = i >> 6, d = i & 63;
                const int row = h * 8 + gr;
                float M = -1e30f;
#pragma unroll
                for (int c = 0; c < NCHUNK; ++c) M = fmaxf(M, m_l[((size_t)row * NCHUNK + c) * 2]);
                float L = 0.f, o = 0.f;
#pragma unroll
                for (int c = 0; c < NCHUNK; ++c) {
                    float w = __expf(m_l[((size_t)row * NCHUNK + c) * 2] - M);
                    L += m_l[((size_t)row * NCHUNK + c) * 2 + 1] * w;
                    o += o_part[((size_t)row * NCHUNK + c) * 64 + d] * w;
                }
                ab[(size_t)GPOS[gr] * EMB + h * 64 + d] = f2bf(o / L);
            }
        }
    }
}

// ---------------------------------------------------------------- launch
extern "C" void kernel_launch(void* const* d_in, const int* in_sizes, int n_in,
                              void* d_out, int out_size, void* d_ws, size_t ws_size,
                              hipStream_t stream) {
    const float* x  = (const float*)d_in[0];
    const float* Wq = (const float*)d_in[1];
    const float* bq = (const float*)d_in[2];
    const float* Wk = (const float*)d_in[3];
    const float* bk = (const float*)d_in[4];
    const float* Wv = (const float*)d_in[5];
    const float* bv = (const float*)d_in[6];
    const float* Wo = (const float*)d_in[7];
    const float* bo = (const float*)d_in[8];

    char* ws = (char*)d_ws;
    unsigned short* xb = (unsigned short*)ws;                   // 8 MB (reused as ab)
    unsigned short* wt = (unsigned short*)(ws + (8u << 20));    // 4 x 2 MB (Wq^T|Wk^T|Wv^T|Wo^T)
    unsigned short* qb = (unsigned short*)(ws + (16u << 20));   // 8 MB
    unsigned short* kb = (unsigned short*)(ws + (24u << 20));   // 8 MB
    unsigned short* vb = (unsigned short*)(ws + (32u << 20));   // 8 MB
    unsigned short* ab = xb;

    float* o_part = (float*)d_out;                               // 512 KB
    float* m_l    = (float*)d_out + 128 * NCHUNK * 64;           // 16 KB
    unsigned short* vtg = (unsigned short*)((char*)d_out + (4u << 20));  // 8 MB
    unsigned int* ctrs  = (unsigned int*)((char*)d_out + (12u << 20));   // 16 head counters

    convert_all<<<3072, 256, 0, stream>>>(x, Wq, Wk, Wv, Wo, (ushort4*)xb, wt, ctrs);

    gemm_qkv<<<(S_LEN / 128) * 24, 256, 0, stream>>>(xb, wt, bq, bk, bv, qb, kb, vb, vtg);

    attn_fused<<<1024 + NHEAD * NCHUNK, 256, 0, stream>>>(qb, kb, vb, vtg, ab, o_part, m_l, ctrs);

    gemm_out<<<(S_LEN / 128) * 16, 256, 0, stream>>>(ab, wt + (3u << 20), bo, (float*)d_out);
}

// Round 15
// 88.720 us; speedup vs baseline: 3.0249x; 1.2121x over previous
//
#include <hip/hip_runtime.h>

typedef __attribute__((ext_vector_type(8))) short short8;
typedef __attribute__((ext_vector_type(8))) __bf16 bf16x8;
typedef __attribute__((ext_vector_type(4))) float f32x4;

#define S_LEN 4096
#define EMB   1024
#define NHEAD 16
#define HDIM  64
#define GCHUNK 256
#define NCHUNK (S_LEN / GCHUNK)   // 16

__constant__ int GPOS[8] = {0, 585, 1170, 1755, 2340, 2925, 3510, 4095};

__device__ __forceinline__ unsigned short f2bf(float f) {
    unsigned int u = __float_as_uint(f);
    u += 0x7fffu + ((u >> 16) & 1u);
    return (unsigned short)(u >> 16);
}
__device__ __forceinline__ float bf2f(unsigned short s) {
    return __uint_as_float(((unsigned int)s) << 16);
}
#define GLOAD16(src, dst) __builtin_amdgcn_global_load_lds( \
    (const __attribute__((address_space(1))) void*)(src),    \
    (__attribute__((address_space(3))) void*)(dst), 16, 0, 0)

// ---------------------------------------------------------------- converts (merged)
__global__ __launch_bounds__(256) void convert_all(const float* __restrict__ x,
                                                   const float* __restrict__ W0,
                                                   const float* __restrict__ W1,
                                                   const float* __restrict__ W2,
                                                   const float* __restrict__ W3,
                                                   ushort4* __restrict__ xb,
                                                   unsigned short* __restrict__ wt) {
    __shared__ float tile[64][65];
    const int t = threadIdx.x;
    if (blockIdx.x < 1024) {
        const int bx = blockIdx.x;
        const int w = bx >> 8, rem = bx & 255;
        const int k0 = (rem >> 4) * 64, n0 = (rem & 15) * 64;
        const float* W = (w == 0) ? W0 : (w == 1) ? W1 : (w == 2) ? W2 : W3;
        unsigned short* dst = wt + (size_t)w * (1u << 20);
        for (int i = t; i < 4096; i += 256) {
            int r = i >> 6, c = i & 63;
            tile[r][c] = W[(size_t)(k0 + r) * EMB + n0 + c];
        }
        __syncthreads();
        for (int i = t; i < 4096; i += 256) {
            int r = i >> 6, c = i & 63;
            dst[(size_t)(n0 + r) * EMB + k0 + c] = f2bf(tile[c][r]);
        }
    } else {
        const int n4 = S_LEN * EMB / 4;
        const float4* in = (const float4*)x;
        for (int i = (blockIdx.x - 1024) * 256 + t; i < n4; i += 2048 * 256) {
            float4 v = in[i];
            ushort4 o;
            o.x = f2bf(v.x); o.y = f2bf(v.y); o.z = f2bf(v.z); o.w = f2bf(v.w);
            xb[i] = o;
        }
    }
}

// ---------------------------------------------------------------- fused QKV GEMM
// counted-vmcnt 2-buffer pipeline; XCD-aware swizzle: each XCD owns bm in [xcd*4,xcd*4+4),
// bn-major within XCD (A panels L2-resident, B tiles shared back-to-back).
__global__ __launch_bounds__(256) void gemm_qkv(const unsigned short* __restrict__ A,
                                                const unsigned short* __restrict__ Bt,
                                                const float* __restrict__ bq,
                                                const float* __restrict__ bk,
                                                const float* __restrict__ bv,
                                                unsigned short* __restrict__ qb,
                                                unsigned short* __restrict__ kb,
                                                unsigned short* __restrict__ vb,
                                                unsigned short* __restrict__ vtg) {
    __shared__ unsigned short As[2][128 * 64];
    __shared__ unsigned short Bs[2][128 * 64];
    const int t = threadIdx.x;
    const int lane = t & 63;
    const int wave = t >> 6;
    const int wm = wave >> 1, wn = wave & 1;
    const int col16 = lane & 15, grp = lane >> 4;
    // 768 blocks = 8 XCDs x (4 bm x 24 bn)
    const int xcd = blockIdx.x & 7;
    const int li  = blockIdx.x >> 3;        // 0..95
    const int bn  = li >> 2;                // 0..23
    const int bm  = xcd * 4 + (li & 3);     // 0..31
    const int sel = bn >> 3, bn_l = bn & 7;
    const float* bias = (sel == 0) ? bq : (sel == 1) ? bk : bv;
    unsigned short* out = (sel == 0) ? qb : (sel == 1) ? kb : vb;

    f32x4 acc[4][4] = {};

    auto stage = [&](int buf, int tstep) {   // exactly 8 global_load_lds / thread
        const int k0 = tstep * 64;
#pragma unroll
        for (int c = 0; c < 4; ++c) {
            int p = t + 256 * c;
            int row = p >> 3, s = p & 7, kc = s ^ (row & 7);
            GLOAD16(A + (size_t)(bm * 128 + row) * EMB + k0 + kc * 8, &As[buf][p * 8]);
        }
#pragma unroll
        for (int c = 0; c < 4; ++c) {
            int p = t + 256 * c;
            int row = p >> 3, s = p & 7, kc = s ^ (row & 7);
            GLOAD16(Bt + (size_t)(bn * 128 + row) * EMB + k0 + kc * 8, &Bs[buf][p * 8]);
        }
    };

    auto compute = [&](int cur) {
        const unsigned short* Ab = As[cur];
        const unsigned short* Bb = Bs[cur];
#pragma unroll
        for (int kk = 0; kk < 2; ++kk) {
            const int kc = kk * 4 + grp;
            bf16x8 af[4], bfr[4];
#pragma unroll
            for (int f = 0; f < 4; ++f) {
                int mrow = wm * 64 + f * 16 + col16;
                short8 ra = *(const short8*)(Ab + (mrow * 8 + (kc ^ (mrow & 7))) * 8);
                af[f] = __builtin_bit_cast(bf16x8, ra);
                int nrow = wn * 64 + f * 16 + col16;
                short8 rb = *(const short8*)(Bb + (nrow * 8 + (kc ^ (nrow & 7))) * 8);
                bfr[f] = __builtin_bit_cast(bf16x8, rb);
            }
#pragma unroll
            for (int fi = 0; fi < 4; ++fi)
#pragma unroll
                for (int fj = 0; fj < 4; ++fj)
                    acc[fi][fj] = __builtin_amdgcn_mfma_f32_16x16x32_bf16(af[fi], bfr[fj], acc[fi][fj], 0, 0, 0);
        }
    };

    stage(0, 0);
    stage(1, 1);                       // 16 loads in flight

#pragma unroll 2
    for (int tstep = 0; tstep < 14; ++tstep) {
        const int cur = tstep & 1;
        asm volatile("s_waitcnt vmcnt(8)" ::: "memory");
        __builtin_amdgcn_s_barrier();
        compute(cur);
        __builtin_amdgcn_s_barrier();
        stage(cur, tstep + 2);
    }
    asm volatile("s_waitcnt vmcnt(8)" ::: "memory");
    __builtin_amdgcn_s_barrier();
    compute(0);
    asm volatile("s_waitcnt vmcnt(0)" ::: "memory");
    __builtin_amdgcn_s_barrier();
    compute(1);

#pragma unroll
    for (int fi = 0; fi < 4; ++fi) {
        const int row0 = bm * 128 + wm * 64 + fi * 16 + grp * 4;
#pragma unroll
        for (int fj = 0; fj < 4; ++fj) {
            const int col = bn_l * 128 + wn * 64 + fj * 16 + col16;
            const float bvv = bias[col];
#pragma unroll
            for (int r = 0; r < 4; ++r)
                out[(size_t)(row0 + r) * EMB + col] = f2bf(acc[fi][fj][r] + bvv);
        }
    }

    if (sel == 2) {
        // transposed V via LDS (XOR-swizzled): T[col][row] then coalesced vtg write
        __syncthreads();
        unsigned short* T = &As[0][0];
#pragma unroll
        for (int fi = 0; fi < 4; ++fi) {
            const int row_l = wm * 64 + fi * 16 + grp * 4;
#pragma unroll
            for (int fj = 0; fj < 4; ++fj) {
                const int col_l = wn * 64 + fj * 16 + col16;
                const float bvv = bias[bn_l * 128 + col_l];
#pragma unroll
                for (int r = 0; r < 4; ++r)
                    T[col_l * 128 + ((row_l + r) ^ ((col_l & 15) << 3))] = f2bf(acc[fi][fj][r] + bvv);
            }
        }
        __syncthreads();
#pragma unroll
        for (int c = 0; c < 8; ++c) {
            int q = t + 256 * c;
            int col = q >> 4, sc = q & 15, s0 = sc * 8;
            short8 v = *(const short8*)(T + col * 128 + (s0 ^ ((col & 15) << 3)));
            *(short8*)(vtg + (size_t)(bn_l * 128 + col) * S_LEN + bm * 128 + s0) = v;
        }
    }
}

// ---------------------------------------------------------------- output GEMM
// BM=128 x BN=64 -> 512 blocks, 48 KB LDS -> 3 blocks/CU; XCD swizzle, counted vmcnt(6)
__global__ __launch_bounds__(256) void gemm_out(const unsigned short* __restrict__ A,
                                                const unsigned short* __restrict__ Bt,
                                                const float* __restrict__ bias,
                                                float* __restrict__ Cout) {
    __shared__ unsigned short As[2][128 * 64];
    __shared__ unsigned short Bs[2][64 * 64];
    const int t = threadIdx.x;
    const int lane = t & 63;
    const int wave = t >> 6;
    const int wm = wave >> 1, wn = wave & 1;
    const int col16 = lane & 15, grp = lane >> 4;
    // 512 blocks = 8 XCDs x (4 bm x 16 bn)
    const int xcd = blockIdx.x & 7;
    const int li  = blockIdx.x >> 3;        // 0..63
    const int bn  = li >> 2;                // 0..15
    const int bm  = xcd * 4 + (li & 3);     // 0..31

    f32x4 acc[4][2] = {};

    auto stage = [&](int buf, int tstep) {   // 6 global_load_lds / thread
        const int k0 = tstep * 64;
#pragma unroll
        for (int c = 0; c < 4; ++c) {
            int p = t + 256 * c;
            int row = p >> 3, s = p & 7, kc = s ^ (row & 7);
            GLOAD16(A + (size_t)(bm * 128 + row) * EMB + k0 + kc * 8, &As[buf][p * 8]);
        }
#pragma unroll
        for (int c = 0; c < 2; ++c) {
            int p = t + 256 * c;
            int row = p >> 3, s = p & 7, kc = s ^ (row & 7);
            GLOAD16(Bt + (size_t)(bn * 64 + row) * EMB + k0 + kc * 8, &Bs[buf][p * 8]);
        }
    };

    auto compute = [&](int cur) {
        const unsigned short* Ab = As[cur];
        const unsigned short* Bb = Bs[cur];
#pragma unroll
        for (int kk = 0; kk < 2; ++kk) {
            const int kc = kk * 4 + grp;
            bf16x8 af[4], bfr[2];
#pragma unroll
            for (int f = 0; f < 4; ++f) {
                int mrow = wm * 64 + f * 16 + col16;
                short8 ra = *(const short8*)(Ab + (mrow * 8 + (kc ^ (mrow & 7))) * 8);
                af[f] = __builtin_bit_cast(bf16x8, ra);
            }
#pragma unroll
            for (int f = 0; f < 2; ++f) {
                int nrow = wn * 32 + f * 16 + col16;
                short8 rb = *(const short8*)(Bb + (nrow * 8 + (kc ^ (nrow & 7))) * 8);
                bfr[f] = __builtin_bit_cast(bf16x8, rb);
            }
#pragma unroll
            for (int fi = 0; fi < 4; ++fi)
#pragma unroll
                for (int fj = 0; fj < 2; ++fj)
                    acc[fi][fj] = __builtin_amdgcn_mfma_f32_16x16x32_bf16(af[fi], bfr[fj], acc[fi][fj], 0, 0, 0);
        }
    };

    stage(0, 0);
    stage(1, 1);                       // 12 loads in flight

#pragma unroll 2
    for (int tstep = 0; tstep < 14; ++tstep) {
        const int cur = tstep & 1;
        asm volatile("s_waitcnt vmcnt(6)" ::: "memory");
        __builtin_amdgcn_s_barrier();
        compute(cur);
        __builtin_amdgcn_s_barrier();
        stage(cur, tstep + 2);
    }
    asm volatile("s_waitcnt vmcnt(6)" ::: "memory");
    __builtin_amdgcn_s_barrier();
    compute(0);
    asm volatile("s_waitcnt vmcnt(0)" ::: "memory");
    __builtin_amdgcn_s_barrier();
    compute(1);

#pragma unroll
    for (int fi = 0; fi < 4; ++fi) {
        const int row0 = bm * 128 + wm * 64 + fi * 16 + grp * 4;
#pragma unroll
        for (int fj = 0; fj < 2; ++fj) {
            const int col = bn * 64 + wn * 32 + fj * 16 + col16;
            const float bvv = bias[col];
#pragma unroll
            for (int r = 0; r < 4; ++r)
                Cout[(size_t)(row0 + r) * EMB + col] = acc[fi][fj][r] + bvv;
        }
    }
}

// ---------------------------------------------------------------- fused attention
__global__ __launch_bounds__(256) void attn_fused(const unsigned short* __restrict__ qb,
                                                  const unsigned short* __restrict__ kb,
                                                  const unsigned short* __restrict__ vb,
                                                  const unsigned short* __restrict__ vtg,
                                                  unsigned short* __restrict__ ab,
                                                  float* __restrict__ o_part,
                                                  float* __restrict__ m_l) {
    __shared__ __align__(16) char smem[43072];
    const int t = threadIdx.x;
    const int lane = t & 63, wave = t >> 6;

    if (blockIdx.x < 1024) {
        unsigned short* Qs  = (unsigned short*)smem;
        unsigned short* Ks  = Qs + 64 * 64;
        unsigned short* Vts = Ks + 80 * 64;
        unsigned short* Ps  = Vts + 64 * 64;
        float* Pg = (float*)(Ps + 64 * 64);
        float* Vg = Pg + 64 * 9;

        const int col16 = lane & 15, grp = lane >> 4;
        const int h = blockIdx.x >> 6, b = blockIdx.x & 63;
        const int bc = h * 64;

#pragma unroll
        for (int c = 0; c < 2; ++c) {
            int p = t + 256 * c, row = p >> 3, s = p & 7, kc = s ^ (row & 7);
            GLOAD16(qb + (size_t)(b * 64 + row) * EMB + bc + kc * 8, Qs + p * 8);
        }
#pragma unroll
        for (int c = 0; c < 3; ++c) {
            int p = t + 256 * c;
            if (p < 576) {
                int row = p >> 3, s = p & 7, kc = s ^ (row & 7);
                int srow = (row < 64) ? (b * 64 + row) : GPOS[row - 64];
                GLOAD16(kb + (size_t)srow * EMB + bc + kc * 8, Ks + p * 8);
            }
        }
        if (t < 64) {
            short8 z = {};
            *(short8*)(Ks + (576 + t) * 8) = z;
        }
#pragma unroll
        for (int c = 0; c < 2; ++c) {
            int p = t + 256 * c, row = p >> 3, s = p & 7, kc = s ^ (row & 7);
            GLOAD16(vtg + (size_t)(bc + row) * S_LEN + b * 64 + kc * 8, Vts + p * 8);
        }
        for (int i = t; i < 512; i += 256) {
            int g = i >> 6, d = i & 63;
            Vg[g * 64 + d] = bf2f(vb[(size_t)GPOS[g] * EMB + bc + d]);
        }
        asm volatile("s_waitcnt vmcnt(0)" ::: "memory");
        __syncthreads();

        f32x4 sc[5] = {};
        const int arow = wave * 16 + col16;
#pragma unroll
        for (int kk = 0; kk < 2; ++kk) {
            const int kc = kk * 4 + grp;
            short8 ra = *(const short8*)(Qs + (arow * 8 + (kc ^ (arow & 7))) * 8);
            bf16x8 af = __builtin_bit_cast(bf16x8, ra);
#pragma unroll
            for (int n = 0; n < 5; ++n) {
                const int brow = n * 16 + col16;
                short8 rb = *(const short8*)(Ks + (brow * 8 + (kc ^ (brow & 7))) * 8);
                sc[n] = __builtin_amdgcn_mfma_f32_16x16x32_bf16(af, __builtin_bit_cast(bf16x8, rb), sc[n], 0, 0, 0);
            }
        }

        const bool valid4 = (col16 < 8) && ((GPOS[col16] >> 6) != b);
#pragma unroll
        for (int r = 0; r < 4; ++r) {
            const int row = wave * 16 + grp * 4 + r;
            float s[5];
#pragma unroll
            for (int n = 0; n < 4; ++n) s[n] = sc[n][r] * 0.125f;
            s[4] = valid4 ? sc[4][r] * 0.125f : -1e30f;
            float m = fmaxf(fmaxf(fmaxf(s[0], s[1]), fmaxf(s[2], s[3])), s[4]);
#pragma unroll
            for (int off = 1; off < 16; off <<= 1) m = fmaxf(m, __shfl_xor(m, off));
            float e[5], l = 0.f;
#pragma unroll
            for (int n = 0; n < 5; ++n) { e[n] = __expf(s[n] - m); l += e[n]; }
#pragma unroll
            for (int off = 1; off < 16; off <<= 1) l += __shfl_xor(l, off);
            const float inv = 1.f / l;
#pragma unroll
            for (int n = 0; n < 4; ++n) {
                const int col = n * 16 + col16;
                const int kc = col >> 3;
                Ps[(row * 8 + (kc ^ (row & 7))) * 8 + (col & 7)] = f2bf(e[n] * inv);
            }
            if (col16 < 8) Pg[row * 9 + col16] = e[4] * inv;
        }
        __syncthreads();

        f32x4 oa[4] = {};
#pragma unroll
        for (int kk = 0; kk < 2; ++kk) {
            const int kc = kk * 4 + grp;
            short8 ra = *(const short8*)(Ps + (arow * 8 + (kc ^ (arow & 7))) * 8);
            bf16x8 af = __builtin_bit_cast(bf16x8, ra);
#pragma unroll
            for (int n = 0; n < 4; ++n) {
                const int drow = n * 16 + col16;
                short8 rb = *(const short8*)(Vts + (drow * 8 + (kc ^ (drow & 7))) * 8);
                oa[n] = __builtin_amdgcn_mfma_f32_16x16x32_bf16(af, __builtin_bit_cast(bf16x8, rb), oa[n], 0, 0, 0);
            }
        }

        float pgr[4][8];
#pragma unroll
        for (int r = 0; r < 4; ++r) {
            const int row = wave * 16 + grp * 4 + r;
#pragma unroll
            for (int g = 0; g < 8; ++g) pgr[r][g] = Pg[row * 9 + g];
        }
#pragma unroll
        for (int n = 0; n < 4; ++n) {
            const int d = n * 16 + col16;
#pragma unroll
            for (int g = 0; g < 8; ++g) {
                const float vg = Vg[g * 64 + d];
#pragma unroll
                for (int r = 0; r < 4; ++r) oa[n][r] += pgr[r][g] * vg;
            }
        }

#pragma unroll
        for (int n = 0; n < 4; ++n) {
            const int d = n * 16 + col16;
#pragma unroll
            for (int r = 0; r < 4; ++r) {
                const int row = wave * 16 + grp * 4 + r;
                ab[(size_t)(b * 64 + row) * EMB + bc + d] = f2bf(oa[n][r]);
            }
        }
    } else {
        float* Qsf = (float*)smem;
        unsigned short* Vs = (unsigned short*)(smem + 2048);
        float* Ps = (float*)(smem + 2048 + 32768);
        float* mfin = Ps + 8 * 256;
        float* lfin = mfin + 8;

        const int bx = blockIdx.x - 1024;
        const int h = bx >> 4;
        const int ch = bx & (NCHUNK - 1);
        const int bc = h * 64;
        const int k0 = ch * GCHUNK;

        for (int i = t; i < 512; i += 256) {
            int r = i >> 6, d = i & 63;
            Qsf[r * 64 + d] = bf2f(qb[(size_t)GPOS[r] * EMB + bc + d]);
        }
        {
            const unsigned short* vrow = vb + (size_t)(k0 + t) * EMB + bc;
#pragma unroll
            for (int c = 0; c < 8; ++c) {
                short8 vv = *(const short8*)(vrow + c * 8);
                *(short8*)(&Vs[t * 64 + (c ^ (t & 7)) * 8]) = vv;
            }
        }
        float kf[64];
        {
            const unsigned short* krow = kb + (size_t)(k0 + t) * EMB + bc;
#pragma unroll
            for (int c = 0; c < 8; ++c) {
                short8 kv = *(const short8*)(krow + c * 8);
#pragma unroll
                for (int j = 0; j < 8; ++j) kf[c * 8 + j] = bf2f((unsigned short)kv[j]);
            }
        }
        __syncthreads();

#pragma unroll
        for (int r = 0; r < 8; ++r) {
            float a0 = 0.f, a1 = 0.f, a2 = 0.f, a3 = 0.f;
#pragma unroll
            for (int c4 = 0; c4 < 16; ++c4) {
                f32x4 q = *(const f32x4*)&Qsf[r * 64 + c4 * 4];
                a0 += q.x * kf[c4 * 4 + 0];
                a1 += q.y * kf[c4 * 4 + 1];
                a2 += q.z * kf[c4 * 4 + 2];
                a3 += q.w * kf[c4 * 4 + 3];
            }
            Ps[r * 256 + t] = (a0 + a1 + a2 + a3) * 0.125f;
        }
        __syncthreads();

#pragma unroll
        for (int rr = 0; rr < 2; ++rr) {
            const int r = wave * 2 + rr;
            float v0 = Ps[r * 256 + lane], v1 = Ps[r * 256 + lane + 64],
                  v2 = Ps[r * 256 + lane + 128], v3 = Ps[r * 256 + lane + 192];
            float m = fmaxf(fmaxf(v0, v1), fmaxf(v2, v3));
#pragma unroll
            for (int off = 1; off < 64; off <<= 1) m = fmaxf(m, __shfl_xor(m, off));
            float e0 = __expf(v0 - m), e1 = __expf(v1 - m), e2 = __expf(v2 - m), e3 = __expf(v3 - m);
            float l = e0 + e1 + e2 + e3;
#pragma unroll
            for (int off = 1; off < 64; off <<= 1) l += __shfl_xor(l, off);
            Ps[r * 256 + lane] = e0; Ps[r * 256 + lane + 64] = e1;
            Ps[r * 256 + lane + 128] = e2; Ps[r * 256 + lane + 192] = e3;
            if (lane == 0) { mfin[r] = m; lfin[r] = l; }
        }
        __syncthreads();

        const int r = t >> 5;
        const int d0 = (t & 31) * 2;
        const int cc = d0 >> 3, ee = d0 & 7;
        float acc0 = 0.f, acc1 = 0.f;
        for (int k = 0; k < GCHUNK; k += 4) {
            f32x4 p = *(const f32x4*)&Ps[r * 256 + k];
#pragma unroll
            for (int j = 0; j < 4; ++j) {
                unsigned int vv = *(const unsigned int*)&Vs[(k + j) * 64 + ((cc ^ ((k + j) & 7)) << 3) + ee];
                acc0 += p[j] * bf2f((unsigned short)(vv & 0xffff));
                acc1 += p[j] * bf2f((unsigned short)(vv >> 16));
            }
        }
        const int rowg = h * 8 + r;
        float* od = o_part + ((size_t)rowg * NCHUNK + ch) * 64 + d0;
        od[0] = acc0; od[1] = acc1;
        if ((t & 31) == 0) {
            m_l[((size_t)rowg * NCHUNK + ch) * 2 + 0] = mfin[r];
            m_l[((size_t)rowg * NCHUNK + ch) * 2 + 1] = lfin[r];
        }
    }
}

__global__ __launch_bounds__(256) void attn_gcomb(const float* __restrict__ o_part,
                                                  const float* __restrict__ m_l,
                                                  unsigned short* __restrict__ ab) {
    const int gid = blockIdx.x * 256 + threadIdx.x;
    const int row = gid >> 6, d = gid & 63;
    float M = -1e30f;
#pragma unroll
    for (int c = 0; c < NCHUNK; ++c) M = fmaxf(M, m_l[((size_t)row * NCHUNK + c) * 2]);
    float L = 0.f, o = 0.f;
#pragma unroll
    for (int c = 0; c < NCHUNK; ++c) {
        float w = __expf(m_l[((size_t)row * NCHUNK + c) * 2] - M);
        L += m_l[((size_t)row * NCHUNK + c) * 2 + 1] * w;
        o += o_part[((size_t)row * NCHUNK + c) * 64 + d] * w;
    }
    const int h = row >> 3, gi = row & 7;
    ab[(size_t)GPOS[gi] * EMB + h * 64 + d] = f2bf(o / L);
}

// ---------------------------------------------------------------- launch
extern "C" void kernel_launch(void* const* d_in, const int* in_sizes, int n_in,
                              void* d_out, int out_size, void* d_ws, size_t ws_size,
                              hipStream_t stream) {
    const float* x  = (const float*)d_in[0];
    const float* Wq = (const float*)d_in[1];
    const float* bq = (const float*)d_in[2];
    const float* Wk = (const float*)d_in[3];
    const float* bk = (const float*)d_in[4];
    const float* Wv = (const float*)d_in[5];
    const float* bv = (const float*)d_in[6];
    const float* Wo = (const float*)d_in[7];
    const float* bo = (const float*)d_in[8];

    char* ws = (char*)d_ws;
    unsigned short* xb = (unsigned short*)ws;                   // 8 MB (reused as ab)
    unsigned short* wt = (unsigned short*)(ws + (8u << 20));    // 4 x 2 MB (Wq^T|Wk^T|Wv^T|Wo^T)
    unsigned short* qb = (unsigned short*)(ws + (16u << 20));   // 8 MB
    unsigned short* kb = (unsigned short*)(ws + (24u << 20));   // 8 MB
    unsigned short* vb = (unsigned short*)(ws + (32u << 20));   // 8 MB
    unsigned short* ab = xb;

    float* o_part = (float*)d_out;                               // 512 KB
    float* m_l    = (float*)d_out + 128 * NCHUNK * 64;           // 16 KB
    unsigned short* vtg = (unsigned short*)((char*)d_out + (4u << 20));  // 8 MB

    convert_all<<<3072, 256, 0, stream>>>(x, Wq, Wk, Wv, Wo, (ushort4*)xb, wt);

    gemm_qkv<<<(S_LEN / 128) * 24, 256, 0, stream>>>(xb, wt, bq, bk, bv, qb, kb, vb, vtg);

    attn_fused<<<1024 + NHEAD * NCHUNK, 256, 0, stream>>>(qb, kb, vb, vtg, ab, o_part, m_l);
    attn_gcomb<<<(128 * 64) / 256, 256, 0, stream>>>(o_part, m_l, ab);

    gemm_out<<<(S_LEN / 128) * 16, 256, 0, stream>>>(ab, wt + (3u << 20), bo, (float*)d_out);
}

// Round 17
// 88.307 us; speedup vs baseline: 3.0391x; 1.0047x over previous
//
#include <hip/hip_runtime.h>

typedef __attribute__((ext_vector_type(8))) short short8;
typedef __attribute__((ext_vector_type(8))) __bf16 bf16x8;
typedef __attribute__((ext_vector_type(4))) float f32x4;

#define S_LEN 4096
#define EMB   1024
#define NHEAD 16
#define HDIM  64
#define GCHUNK 256
#define NCHUNK (S_LEN / GCHUNK)   // 16

__constant__ int GPOS[8] = {0, 585, 1170, 1755, 2340, 2925, 3510, 4095};

__device__ __forceinline__ unsigned short f2bf(float f) {
    unsigned int u = __float_as_uint(f);
    u += 0x7fffu + ((u >> 16) & 1u);
    return (unsigned short)(u >> 16);
}
__device__ __forceinline__ float bf2f(unsigned short s) {
    return __uint_as_float(((unsigned int)s) << 16);
}
#define GLOAD16(src, dst) __builtin_amdgcn_global_load_lds( \
    (const __attribute__((address_space(1))) void*)(src),    \
    (__attribute__((address_space(3))) void*)(dst), 16, 0, 0)

// ---------------------------------------------------------------- converts (merged)
__global__ __launch_bounds__(256) void convert_all(const float* __restrict__ x,
                                                   const float* __restrict__ W0,
                                                   const float* __restrict__ W1,
                                                   const float* __restrict__ W2,
                                                   const float* __restrict__ W3,
                                                   ushort4* __restrict__ xb,
                                                   unsigned short* __restrict__ wt) {
    __shared__ float tile[64][65];
    const int t = threadIdx.x;
    if (blockIdx.x < 1024) {
        const int bx = blockIdx.x;
        const int w = bx >> 8, rem = bx & 255;
        const int k0 = (rem >> 4) * 64, n0 = (rem & 15) * 64;
        const float* W = (w == 0) ? W0 : (w == 1) ? W1 : (w == 2) ? W2 : W3;
        unsigned short* dst = wt + (size_t)w * (1u << 20);
        for (int i = t; i < 4096; i += 256) {
            int r = i >> 6, c = i & 63;
            tile[r][c] = W[(size_t)(k0 + r) * EMB + n0 + c];
        }
        __syncthreads();
        for (int i = t; i < 4096; i += 256) {
            int r = i >> 6, c = i & 63;
            dst[(size_t)(n0 + r) * EMB + k0 + c] = f2bf(tile[c][r]);
        }
    } else {
        const int n4 = S_LEN * EMB / 4;
        const float4* in = (const float4*)x;
        for (int i = (blockIdx.x - 1024) * 256 + t; i < n4; i += 2048 * 256) {
            float4 v = in[i];
            ushort4 o;
            o.x = f2bf(v.x); o.y = f2bf(v.y); o.z = f2bf(v.z); o.w = f2bf(v.w);
            xb[i] = o;
        }
    }
}

// ---------------------------------------------------------------- fused QKV GEMM (R15-proven)
__global__ __launch_bounds__(256) void gemm_qkv(const unsigned short* __restrict__ A,
                                                const unsigned short* __restrict__ Bt,
                                                const float* __restrict__ bq,
                                                const float* __restrict__ bk,
                                                const float* __restrict__ bv,
                                                unsigned short* __restrict__ qb,
                                                unsigned short* __restrict__ kb,
                                                unsigned short* __restrict__ vb,
                                                unsigned short* __restrict__ vtg) {
    __shared__ unsigned short As[2][128 * 64];
    __shared__ unsigned short Bs[2][128 * 64];
    const int t = threadIdx.x;
    const int lane = t & 63;
    const int wave = t >> 6;
    const int wm = wave >> 1, wn = wave & 1;
    const int col16 = lane & 15, grp = lane >> 4;
    const int xcd = blockIdx.x & 7;
    const int li  = blockIdx.x >> 3;
    const int bn  = li >> 2;
    const int bm  = xcd * 4 + (li & 3);
    const int sel = bn >> 3, bn_l = bn & 7;
    const float* bias = (sel == 0) ? bq : (sel == 1) ? bk : bv;
    unsigned short* out = (sel == 0) ? qb : (sel == 1) ? kb : vb;

    f32x4 acc[4][4] = {};

    auto stage = [&](int buf, int tstep) {
        const int k0 = tstep * 64;
#pragma unroll
        for (int c = 0; c < 4; ++c) {
            int p = t + 256 * c;
            int row = p >> 3, s = p & 7, kc = s ^ (row & 7);
            GLOAD16(A + (size_t)(bm * 128 + row) * EMB + k0 + kc * 8, &As[buf][p * 8]);
        }
#pragma unroll
        for (int c = 0; c < 4; ++c) {
            int p = t + 256 * c;
            int row = p >> 3, s = p & 7, kc = s ^ (row & 7);
            GLOAD16(Bt + (size_t)(bn * 128 + row) * EMB + k0 + kc * 8, &Bs[buf][p * 8]);
        }
    };

    auto compute = [&](int cur) {
        const unsigned short* Ab = As[cur];
        const unsigned short* Bb = Bs[cur];
#pragma unroll
        for (int kk = 0; kk < 2; ++kk) {
            const int kc = kk * 4 + grp;
            bf16x8 af[4], bfr[4];
#pragma unroll
            for (int f = 0; f < 4; ++f) {
                int mrow = wm * 64 + f * 16 + col16;
                short8 ra = *(const short8*)(Ab + (mrow * 8 + (kc ^ (mrow & 7))) * 8);
                af[f] = __builtin_bit_cast(bf16x8, ra);
                int nrow = wn * 64 + f * 16 + col16;
                short8 rb = *(const short8*)(Bb + (nrow * 8 + (kc ^ (nrow & 7))) * 8);
                bfr[f] = __builtin_bit_cast(bf16x8, rb);
            }
#pragma unroll
            for (int fi = 0; fi < 4; ++fi)
#pragma unroll
                for (int fj = 0; fj < 4; ++fj)
                    acc[fi][fj] = __builtin_amdgcn_mfma_f32_16x16x32_bf16(af[fi], bfr[fj], acc[fi][fj], 0, 0, 0);
        }
    };

    stage(0, 0);
    stage(1, 1);

#pragma unroll 2
    for (int tstep = 0; tstep < 14; ++tstep) {
        const int cur = tstep & 1;
        asm volatile("s_waitcnt vmcnt(8)" ::: "memory");
        __builtin_amdgcn_s_barrier();
        compute(cur);
        __builtin_amdgcn_s_barrier();
        stage(cur, tstep + 2);
    }
    asm volatile("s_waitcnt vmcnt(8)" ::: "memory");
    __builtin_amdgcn_s_barrier();
    compute(0);
    asm volatile("s_waitcnt vmcnt(0)" ::: "memory");
    __builtin_amdgcn_s_barrier();
    compute(1);

#pragma unroll
    for (int fi = 0; fi < 4; ++fi) {
        const int row0 = bm * 128 + wm * 64 + fi * 16 + grp * 4;
#pragma unroll
        for (int fj = 0; fj < 4; ++fj) {
            const int col = bn_l * 128 + wn * 64 + fj * 16 + col16;
            const float bvv = bias[col];
#pragma unroll
            for (int r = 0; r < 4; ++r)
                out[(size_t)(row0 + r) * EMB + col] = f2bf(acc[fi][fj][r] + bvv);
        }
    }

    if (sel == 2) {
        __syncthreads();
        unsigned short* T = &As[0][0];
#pragma unroll
        for (int fi = 0; fi < 4; ++fi) {
            const int row_l = wm * 64 + fi * 16 + grp * 4;
#pragma unroll
            for (int fj = 0; fj < 4; ++fj) {
                const int col_l = wn * 64 + fj * 16 + col16;
                const float bvv = bias[bn_l * 128 + col_l];
#pragma unroll
                for (int r = 0; r < 4; ++r)
                    T[col_l * 128 + ((row_l + r) ^ ((col_l & 15) << 3))] = f2bf(acc[fi][fj][r] + bvv);
            }
        }
        __syncthreads();
#pragma unroll
        for (int c = 0; c < 8; ++c) {
            int q = t + 256 * c;
            int col = q >> 4, sc = q & 15, s0 = sc * 8;
            short8 v = *(const short8*)(T + col * 128 + (s0 ^ ((col & 15) << 3)));
            *(short8*)(vtg + (size_t)(bn_l * 128 + col) * S_LEN + bm * 128 + s0) = v;
        }
    }
}

// ---------------------------------------------------------------- output GEMM (R15-proven)
__global__ __launch_bounds__(256) void gemm_out(const unsigned short* __restrict__ A,
                                                const unsigned short* __restrict__ Bt,
                                                const float* __restrict__ bias,
                                                float* __restrict__ Cout) {
    __shared__ unsigned short As[2][128 * 64];
    __shared__ unsigned short Bs[2][64 * 64];
    const int t = threadIdx.x;
    const int lane = t & 63;
    const int wave = t >> 6;
    const int wm = wave >> 1, wn = wave & 1;
    const int col16 = lane & 15, grp = lane >> 4;
    const int xcd = blockIdx.x & 7;
    const int li  = blockIdx.x >> 3;
    const int bn  = li >> 2;
    const int bm  = xcd * 4 + (li & 3);

    f32x4 acc[4][2] = {};

    auto stage = [&](int buf, int tstep) {
        const int k0 = tstep * 64;
#pragma unroll
        for (int c = 0; c < 4; ++c) {
            int p = t + 256 * c;
            int row = p >> 3, s = p & 7, kc = s ^ (row & 7);
            GLOAD16(A + (size_t)(bm * 128 + row) * EMB + k0 + kc * 8, &As[buf][p * 8]);
        }
#pragma unroll
        for (int c = 0; c < 2; ++c) {
            int p = t + 256 * c;
            int row = p >> 3, s = p & 7, kc = s ^ (row & 7);
            GLOAD16(Bt + (size_t)(bn * 64 + row) * EMB + k0 + kc * 8, &Bs[buf][p * 8]);
        }
    };

    auto compute = [&](int cur) {
        const unsigned short* Ab = As[cur];
        const unsigned short* Bb = Bs[cur];
#pragma unroll
        for (int kk = 0; kk < 2; ++kk) {
            const int kc = kk * 4 + grp;
            bf16x8 af[4], bfr[2];
#pragma unroll
            for (int f = 0; f < 4; ++f) {
                int mrow = wm * 64 + f * 16 + col16;
                short8 ra = *(const short8*)(Ab + (mrow * 8 + (kc ^ (mrow & 7))) * 8);
                af[f] = __builtin_bit_cast(bf16x8, ra);
            }
#pragma unroll
            for (int f = 0; f < 2; ++f) {
                int nrow = wn * 32 + f * 16 + col16;
                short8 rb = *(const short8*)(Bb + (nrow * 8 + (kc ^ (nrow & 7))) * 8);
                bfr[f] = __builtin_bit_cast(bf16x8, rb);
            }
#pragma unroll
            for (int fi = 0; fi < 4; ++fi)
#pragma unroll
                for (int fj = 0; fj < 2; ++fj)
                    acc[fi][fj] = __builtin_amdgcn_mfma_f32_16x16x32_bf16(af[fi], bfr[fj], acc[fi][fj], 0, 0, 0);
        }
    };

    stage(0, 0);
    stage(1, 1);

#pragma unroll 2
    for (int tstep = 0; tstep < 14; ++tstep) {
        const int cur = tstep & 1;
        asm volatile("s_waitcnt vmcnt(6)" ::: "memory");
        __builtin_amdgcn_s_barrier();
        compute(cur);
        __builtin_amdgcn_s_barrier();
        stage(cur, tstep + 2);
    }
    asm volatile("s_waitcnt vmcnt(6)" ::: "memory");
    __builtin_amdgcn_s_barrier();
    compute(0);
    asm volatile("s_waitcnt vmcnt(0)" ::: "memory");
    __builtin_amdgcn_s_barrier();
    compute(1);

#pragma unroll
    for (int fi = 0; fi < 4; ++fi) {
        const int row0 = bm * 128 + wm * 64 + fi * 16 + grp * 4;
#pragma unroll
        for (int fj = 0; fj < 2; ++fj) {
            const int col = bn * 64 + wn * 32 + fj * 16 + col16;
            const float bvv = bias[col];
#pragma unroll
            for (int r = 0; r < 4; ++r)
                Cout[(size_t)(row0 + r) * EMB + col] = acc[fi][fj][r] + bvv;
        }
    }
}

// ---------------------------------------------------------------- fused attention
// local branch: counted-vmcnt staging (QK^T overlaps V staging) + setprio on MFMA clusters
__global__ __launch_bounds__(256) void attn_fused(const unsigned short* __restrict__ qb,
                                                  const unsigned short* __restrict__ kb,
                                                  const unsigned short* __restrict__ vb,
                                                  const unsigned short* __restrict__ vtg,
                                                  unsigned short* __restrict__ ab,
                                                  float* __restrict__ o_part,
                                                  float* __restrict__ m_l) {
    __shared__ __align__(16) char smem[43072];
    const int t = threadIdx.x;
    const int lane = t & 63, wave = t >> 6;

    if (blockIdx.x < 1024) {
        unsigned short* Qs  = (unsigned short*)smem;
        unsigned short* Ks  = Qs + 64 * 64;
        unsigned short* Vts = Ks + 80 * 64;
        unsigned short* Ps  = Vts + 64 * 64;
        float* Pg = (float*)(Ps + 64 * 64);
        float* Vg = Pg + 64 * 9;

        const int col16 = lane & 15, grp = lane >> 4;
        const int h = blockIdx.x >> 6, b = blockIdx.x & 63;
        const int bc = h * 64;

        // ---- group 1: Q + K gloads (needed for QK^T)
#pragma unroll
        for (int c = 0; c < 2; ++c) {
            int p = t + 256 * c, row = p >> 3, s = p & 7, kc = s ^ (row & 7);
            GLOAD16(qb + (size_t)(b * 64 + row) * EMB + bc + kc * 8, Qs + p * 8);
        }
#pragma unroll
        for (int c = 0; c < 3; ++c) {
            int p = t + 256 * c;
            if (p < 576) {
                int row = p >> 3, s = p & 7, kc = s ^ (row & 7);
                int srow = (row < 64) ? (b * 64 + row) : GPOS[row - 64];
                GLOAD16(kb + (size_t)srow * EMB + bc + kc * 8, Ks + p * 8);
            }
        }
        if (t < 64) {
            short8 z = {};
            *(short8*)(Ks + (576 + t) * 8) = z;
        }
        asm volatile("" ::: "memory");   // pin group order: Q,K issued before Vt,Vg

        // ---- group 2: Vt gloads + Vg reg loads (needed only at PV)
#pragma unroll
        for (int c = 0; c < 2; ++c) {
            int p = t + 256 * c, row = p >> 3, s = p & 7, kc = s ^ (row & 7);
            GLOAD16(vtg + (size_t)(bc + row) * S_LEN + b * 64 + kc * 8, Vts + p * 8);
        }
        const int gi0 = t, gi1 = t + 256;
        unsigned short vg0 = vb[(size_t)GPOS[gi0 >> 6] * EMB + bc + (gi0 & 63)];
        unsigned short vg1 = vb[(size_t)GPOS[gi1 >> 6] * EMB + bc + (gi1 & 63)];

        // wait for Q,K only (vmcnt retires in issue order; Vt2+Vg2 stay in flight)
        asm volatile("s_waitcnt vmcnt(4) lgkmcnt(0)" ::: "memory");
        __builtin_amdgcn_s_barrier();
        asm volatile("" ::: "memory");

        f32x4 sc[5] = {};
        const int arow = wave * 16 + col16;
        __builtin_amdgcn_s_setprio(1);
#pragma unroll
        for (int kk = 0; kk < 2; ++kk) {
            const int kc = kk * 4 + grp;
            short8 ra = *(const short8*)(Qs + (arow * 8 + (kc ^ (arow & 7))) * 8);
            bf16x8 af = __builtin_bit_cast(bf16x8, ra);
#pragma unroll
            for (int n = 0; n < 5; ++n) {
                const int brow = n * 16 + col16;
                short8 rb = *(const short8*)(Ks + (brow * 8 + (kc ^ (brow & 7))) * 8);
                sc[n] = __builtin_amdgcn_mfma_f32_16x16x32_bf16(af, __builtin_bit_cast(bf16x8, rb), sc[n], 0, 0, 0);
            }
        }
        __builtin_amdgcn_s_setprio(0);

        const bool valid4 = (col16 < 8) && ((GPOS[col16] >> 6) != b);
#pragma unroll
        for (int r = 0; r < 4; ++r) {
            const int row = wave * 16 + grp * 4 + r;
            float s[5];
#pragma unroll
            for (int n = 0; n < 4; ++n) s[n] = sc[n][r] * 0.125f;
            s[4] = valid4 ? sc[4][r] * 0.125f : -1e30f;
            float m = fmaxf(fmaxf(fmaxf(s[0], s[1]), fmaxf(s[2], s[3])), s[4]);
#pragma unroll
            for (int off = 1; off < 16; off <<= 1) m = fmaxf(m, __shfl_xor(m, off));
            float e[5], l = 0.f;
#pragma unroll
            for (int n = 0; n < 5; ++n) { e[n] = __expf(s[n] - m); l += e[n]; }
#pragma unroll
            for (int off = 1; off < 16; off <<= 1) l += __shfl_xor(l, off);
            const float inv = 1.f / l;
#pragma unroll
            for (int n = 0; n < 4; ++n) {
                const int col = n * 16 + col16;
                const int kc = col >> 3;
                Ps[(row * 8 + (kc ^ (row & 7))) * 8 + (col & 7)] = f2bf(e[n] * inv);
            }
            if (col16 < 8) Pg[row * 9 + col16] = e[4] * inv;
        }

        // Vt now needed; Vg regs ready -> LDS
        asm volatile("s_waitcnt vmcnt(0)" ::: "memory");
        Vg[(gi0 >> 6) * 64 + (gi0 & 63)] = bf2f(vg0);
        Vg[(gi1 >> 6) * 64 + (gi1 & 63)] = bf2f(vg1);
        __syncthreads();

        f32x4 oa[4] = {};
        __builtin_amdgcn_s_setprio(1);
#pragma unroll
        for (int kk = 0; kk < 2; ++kk) {
            const int kc = kk * 4 + grp;
            short8 ra = *(const short8*)(Ps + (arow * 8 + (kc ^ (arow & 7))) * 8);
            bf16x8 af = __builtin_bit_cast(bf16x8, ra);
#pragma unroll
            for (int n = 0; n < 4; ++n) {
                const int drow = n * 16 + col16;
                short8 rb = *(const short8*)(Vts + (drow * 8 + (kc ^ (drow & 7))) * 8);
                oa[n] = __builtin_amdgcn_mfma_f32_16x16x32_bf16(af, __builtin_bit_cast(bf16x8, rb), oa[n], 0, 0, 0);
            }
        }
        __builtin_amdgcn_s_setprio(0);

        float pgr[4][8];
#pragma unroll
        for (int r = 0; r < 4; ++r) {
            const int row = wave * 16 + grp * 4 + r;
#pragma unroll
            for (int g = 0; g < 8; ++g) pgr[r][g] = Pg[row * 9 + g];
        }
#pragma unroll
        for (int n = 0; n < 4; ++n) {
            const int d = n * 16 + col16;
#pragma unroll
            for (int g = 0; g < 8; ++g) {
                const float vg = Vg[g * 64 + d];
#pragma unroll
                for (int r = 0; r < 4; ++r) oa[n][r] += pgr[r][g] * vg;
            }
        }

#pragma unroll
        for (int n = 0; n < 4; ++n) {
            const int d = n * 16 + col16;
#pragma unroll
            for (int r = 0; r < 4; ++r) {
                const int row = wave * 16 + grp * 4 + r;
                ab[(size_t)(b * 64 + row) * EMB + bc + d] = f2bf(oa[n][r]);
            }
        }
    } else {
        float* Qsf = (float*)smem;
        unsigned short* Vs = (unsigned short*)(smem + 2048);
        float* Ps = (float*)(smem + 2048 + 32768);
        float* mfin = Ps + 8 * 256;
        float* lfin = mfin + 8;

        const int bx = blockIdx.x - 1024;
        const int h = bx >> 4;
        const int ch = bx & (NCHUNK - 1);
        const int bc = h * 64;
        const int k0 = ch * GCHUNK;

        for (int i = t; i < 512; i += 256) {
            int r = i >> 6, d = i & 63;
            Qsf[r * 64 + d] = bf2f(qb[(size_t)GPOS[r] * EMB + bc + d]);
        }
        {
            const unsigned short* vrow = vb + (size_t)(k0 + t) * EMB + bc;
#pragma unroll
            for (int c = 0; c < 8; ++c) {
                short8 vv = *(const short8*)(vrow + c * 8);
                *(short8*)(&Vs[t * 64 + (c ^ (t & 7)) * 8]) = vv;
            }
        }
        float kf[64];
        {
            const unsigned short* krow = kb + (size_t)(k0 + t) * EMB + bc;
#pragma unroll
            for (int c = 0; c < 8; ++c) {
                short8 kv = *(const short8*)(krow + c * 8);
#pragma unroll
                for (int j = 0; j < 8; ++j) kf[c * 8 + j] = bf2f((unsigned short)kv[j]);
            }
        }
        __syncthreads();

#pragma unroll
        for (int r = 0; r < 8; ++r) {
            float a0 = 0.f, a1 = 0.f, a2 = 0.f, a3 = 0.f;
#pragma unroll
            for (int c4 = 0; c4 < 16; ++c4) {
                f32x4 q = *(const f32x4*)&Qsf[r * 64 + c4 * 4];
                a0 += q.x * kf[c4 * 4 + 0];
                a1 += q.y * kf[c4 * 4 + 1];
                a2 += q.z * kf[c4 * 4 + 2];
                a3 += q.w * kf[c4 * 4 + 3];
            }
            Ps[r * 256 + t] = (a0 + a1 + a2 + a3) * 0.125f;
        }
        __syncthreads();

#pragma unroll
        for (int rr = 0; rr < 2; ++rr) {
            const int r = wave * 2 + rr;
            float v0 = Ps[r * 256 + lane], v1 = Ps[r * 256 + lane + 64],
                  v2 = Ps[r * 256 + lane + 128], v3 = Ps[r * 256 + lane + 192];
            float m = fmaxf(fmaxf(v0, v1), fmaxf(v2, v3));
#pragma unroll
            for (int off = 1; off < 64; off <<= 1) m = fmaxf(m, __shfl_xor(m, off));
            float e0 = __expf(v0 - m), e1 = __expf(v1 - m), e2 = __expf(v2 - m), e3 = __expf(v3 - m);
            float l = e0 + e1 + e2 + e3;
#pragma unroll
            for (int off = 1; off < 64; off <<= 1) l += __shfl_xor(l, off);
            Ps[r * 256 + lane] = e0; Ps[r * 256 + lane + 64] = e1;
            Ps[r * 256 + lane + 128] = e2; Ps[r * 256 + lane + 192] = e3;
            if (lane == 0) { mfin[r] = m; lfin[r] = l; }
        }
        __syncthreads();

        const int r = t >> 5;
        const int d0 = (t & 31) * 2;
        const int cc = d0 >> 3, ee = d0 & 7;
        float acc0 = 0.f, acc1 = 0.f;
        for (int k = 0; k < GCHUNK; k += 4) {
            f32x4 p = *(const f32x4*)&Ps[r * 256 + k];
#pragma unroll
            for (int j = 0; j < 4; ++j) {
                unsigned int vv = *(const unsigned int*)&Vs[(k + j) * 64 + ((cc ^ ((k + j) & 7)) << 3) + ee];
                acc0 += p[j] * bf2f((unsigned short)(vv & 0xffff));
                acc1 += p[j] * bf2f((unsigned short)(vv >> 16));
            }
        }
        const int rowg = h * 8 + r;
        float* od = o_part + ((size_t)rowg * NCHUNK + ch) * 64 + d0;
        od[0] = acc0; od[1] = acc1;
        if ((t & 31) == 0) {
            m_l[((size_t)rowg * NCHUNK + ch) * 2 + 0] = mfin[r];
            m_l[((size_t)rowg * NCHUNK + ch) * 2 + 1] = lfin[r];
        }
    }
}

__global__ __launch_bounds__(256) void attn_gcomb(const float* __restrict__ o_part,
                                                  const float* __restrict__ m_l,
                                                  unsigned short* __restrict__ ab) {
    const int gid = blockIdx.x * 256 + threadIdx.x;
    const int row = gid >> 6, d = gid & 63;
    float M = -1e30f;
#pragma unroll
    for (int c = 0; c < NCHUNK; ++c) M = fmaxf(M, m_l[((size_t)row * NCHUNK + c) * 2]);
    float L = 0.f, o = 0.f;
#pragma unroll
    for (int c = 0; c < NCHUNK; ++c) {
        float w = __expf(m_l[((size_t)row * NCHUNK + c) * 2] - M);
        L += m_l[((size_t)row * NCHUNK + c) * 2 + 1] * w;
        o += o_part[((size_t)row * NCHUNK + c) * 64 + d] * w;
    }
    const int h = row >> 3, gi = row & 7;
    ab[(size_t)GPOS[gi] * EMB + h * 64 + d] = f2bf(o / L);
}

// ---------------------------------------------------------------- launch
extern "C" void kernel_launch(void* const* d_in, const int* in_sizes, int n_in,
                              void* d_out, int out_size, void* d_ws, size_t ws_size,
                              hipStream_t stream) {
    const float* x  = (const float*)d_in[0];
    const float* Wq = (const float*)d_in[1];
    const float* bq = (const float*)d_in[2];
    const float* Wk = (const float*)d_in[3];
    const float* bk = (const float*)d_in[4];
    const float* Wv = (const float*)d_in[5];
    const float* bv = (const float*)d_in[6];
    const float* Wo = (const float*)d_in[7];
    const float* bo = (const float*)d_in[8];

    char* ws = (char*)d_ws;
    unsigned short* xb = (unsigned short*)ws;                   // 8 MB (reused as ab)
    unsigned short* wt = (unsigned short*)(ws + (8u << 20));    // 4 x 2 MB (Wq^T|Wk^T|Wv^T|Wo^T)
    unsigned short* qb = (unsigned short*)(ws + (16u << 20));   // 8 MB
    unsigned short* kb = (unsigned short*)(ws + (24u << 20));   // 8 MB
    unsigned short* vb = (unsigned short*)(ws + (32u << 20));   // 8 MB
    unsigned short* ab = xb;

    float* o_part = (float*)d_out;                               // 512 KB
    float* m_l    = (float*)d_out + 128 * NCHUNK * 64;           // 16 KB
    unsigned short* vtg = (unsigned short*)((char*)d_out + (4u << 20));  // 8 MB

    convert_all<<<3072, 256, 0, stream>>>(x, Wq, Wk, Wv, Wo, (ushort4*)xb, wt);

    gemm_qkv<<<(S_LEN / 128) * 24, 256, 0, stream>>>(xb, wt, bq, bk, bv, qb, kb, vb, vtg);

    attn_fused<<<1024 + NHEAD * NCHUNK, 256, 0, stream>>>(qb, kb, vb, vtg, ab, o_part, m_l);
    attn_gcomb<<<(128 * 64) / 256, 256, 0, stream>>>(o_part, m_l, ab);

    gemm_out<<<(S_LEN / 128) * 16, 256, 0, stream>>>(ab, wt + (3u << 20), bo, (float*)d_out);
}